// Round 7
// baseline (363.756 us; speedup 1.0000x reference)
//
#include <hip/hip_runtime.h>
#include <hip/hip_bf16.h>

#define BB 32
#define SS 256
#define DD 128
#define GG 128
#define NG 512   // 4*(H/2) gate columns per direction
#define LL 32
#define LOG2E 1.4426950408889634f

typedef unsigned short u16;
typedef __attribute__((ext_vector_type(8))) short short8;
typedef __attribute__((ext_vector_type(4))) float f32x4;

__device__ __forceinline__ float bf2f(u16 u){ return __uint_as_float(((unsigned)u)<<16); }
__device__ __forceinline__ u16 f2bf(float f){
    unsigned x = __float_as_uint(f);
    unsigned r = x + 0x7fffu + ((x>>16)&1u);
    return (u16)(r>>16);
}
__device__ __forceinline__ float tanh_f(float x){ float e=__expf(2.0f*x); return 1.0f - 2.0f/(e+1.0f); }

__device__ __forceinline__ float exp2_f(float x){
#if __has_builtin(__builtin_amdgcn_exp2f)
    return __builtin_amdgcn_exp2f(x);
#elif __has_builtin(__builtin_amdgcn_expf)
    return __builtin_amdgcn_expf(x);
#else
    return __expf(x * 0.6931471805599453f);
#endif
}
__device__ __forceinline__ float rcp_f(float x){
#if __has_builtin(__builtin_amdgcn_rcpf)
    return __builtin_amdgcn_rcpf(x);
#else
    return 1.0f / x;
#endif
}

// ---------------- kprep: per-block dtype flag + canonicalize + transposes + label-norm ----------------
// type 0: can[p0+i] = f32(src[i])
// type 1: WcatT[(p0 + i>>7)*128 + (i&127)] = bf16(src[(i&127)*p1 + (i>>7)])
// type 2: (p0? memWT : tagWT)[(i&31)*256 + (i>>5)] = bf16(src[(i>>5)*32 + (i&31)])
// type 3: label embedding row-norm -> WcatT cols 1152..1183 (+ zero pad 1184..1215)
struct PJobs { const void* src[21]; int n[21]; int p0[21]; int p1[21]; int type[21]; };

__global__ void kprep(PJobs jb, const void* __restrict__ wemb, int* __restrict__ flags,
                      float* __restrict__ can,
                      u16* __restrict__ WcatT, u16* __restrict__ tagWT, u16* __restrict__ memWT){
    int t = threadIdx.x;
    // local dtype probe: f32 low-mantissa halves have uniform exponent field >= 0x90
    __shared__ int cw[4];
    __shared__ int sflag;
    {
        u16 v = ((const u16*)wemb)[2*t];
        int e = (v>>7)&0xFF;
        int c = (e>=0x90)?1:0;
        #pragma unroll
        for (int mk=32; mk>0; mk>>=1) c += __shfl_xor(c, mk);
        if ((t&63)==0) cw[t>>6] = c;
        __syncthreads();
        if (t==0) sflag = (cw[0]+cw[1]+cw[2]+cw[3] >= 32) ? 1 : 0;
        __syncthreads();
    }
    int f = sflag;
    if (blockIdx.x==0 && blockIdx.y==0 && t==0) flags[0] = f;

    int id = blockIdx.y;
    int i = blockIdx.x*256 + t;
    if (i >= jb.n[id]) return;
    const void* src = jb.src[id];
    int p0 = jb.p0[id];
    int ty = jb.type[id];
    if (ty == 0){
        float v = f ? ((const float*)src)[i] : bf2f(((const u16*)src)[i]);
        can[p0 + i] = v;
    } else if (ty == 1){
        int c = i>>7, k = i&127;
        float v = f ? ((const float*)src)[k*jb.p1[id] + c] : bf2f(((const u16*)src)[k*jb.p1[id] + c]);
        WcatT[(size_t)(p0 + c)*128 + k] = f2bf(v);
    } else if (ty == 2){
        int l = i&31, k = i>>5;
        float v = f ? ((const float*)src)[k*32 + l] : bf2f(((const u16*)src)[k*32 + l]);
        (p0 ? memWT : tagWT)[l*256 + k] = f2bf(v);
    } else {
        // i < 4096: row = i>>7 (0..31), col = i&127; block covers rows 2bx, 2bx+1
        int row = i>>7, col = i&127;
        float v = f ? ((const float*)src)[i] : bf2f(((const u16*)src)[i]);
        float sq = v*v;
        #pragma unroll
        for (int mk=32; mk>0; mk>>=1) sq += __shfl_xor(sq, mk);
        __shared__ float r4[4];
        if ((t&63)==0) r4[t>>6] = sq;
        __syncthreads();
        int half = t>>7;
        float tot = r4[half*2] + r4[half*2+1];
        float inv = 1.0f/(sqrtf(tot) + 1e-8f);
        WcatT[(size_t)(1152+row)*128 + col] = f2bf(v*inv);
        WcatT[(size_t)(1184+row)*128 + col] = 0;   // pad cols
    }
}

// ---------------- k1: gather + norm -> weC (bf16), invn ----------------
__global__ void k1_token(const int* __restrict__ wid, const void* __restrict__ wemb,
                         const int* __restrict__ flags,
                         u16* __restrict__ weC, float* __restrict__ invn){
    int blk = blockIdx.x;          // b*256+s
    int t = threadIdx.x;           // 128
    int idx = wid[blk];
    float wv = flags[0] ? ((const float*)wemb)[(size_t)idx*DD + t]
                        : bf2f(((const u16*)wemb)[(size_t)idx*DD + t]);
    int b = blk>>8, s = blk&255;
    int m = s*BB + b;
    weC[(size_t)m*DD + t] = f2bf(wv);
    float sq = wv*wv;
    #pragma unroll
    for (int mk=32; mk>0; mk>>=1) sq += __shfl_xor(sq, mk);
    __shared__ float red2[2];
    if ((t&63)==0) red2[t>>6] = sq;
    __syncthreads();
    if (t==0) invn[m] = 1.0f/(sqrtf(red2[0]+red2[1]) + 1e-8f);
}

// ---------------- kgemm: [gpre4 | sent_h | lab_e] = weC(bf16) @ WcatT(bf16), MFMA ----------------
__global__ __launch_bounds__(256) void kgemm(const u16* __restrict__ weC,
                      const u16* __restrict__ WcatT,
                      const float* __restrict__ invn, const float* __restrict__ sentBc,
                      float* __restrict__ gpre4, float* __restrict__ sent_h,
                      float* __restrict__ lab_e){
    int mt = blockIdx.x;            // 0..127
    int nb = blockIdx.y;            // 0..18
    int t = threadIdx.x;
    int w4 = t>>6, l = t&63, li = l&15, lg = l>>4;
    int mbase = mt*64 + w4*16;
    int n0 = nb*64;
    short8 af[4];
    #pragma unroll
    for (int ks=0;ks<4;ks++)
        af[ks] = *(const short8*)&weC[(size_t)(mbase + li)*128 + ks*32 + lg*8];
    f32x4 acc[4];
    #pragma unroll
    for (int nt=0;nt<4;nt++){
        short8 bf[4];
        #pragma unroll
        for (int ks=0;ks<4;ks++)
            bf[ks] = *(const short8*)&WcatT[(size_t)(n0 + nt*16 + li)*128 + ks*32 + lg*8];
        f32x4 a; a[0]=0.f; a[1]=0.f; a[2]=0.f; a[3]=0.f;
        #pragma unroll
        for (int ks=0;ks<4;ks++)
            a = __builtin_amdgcn_mfma_f32_16x16x32_bf16(af[ks], bf[ks], a, 0,0,0);
        acc[nt] = a;
    }
    int mrow = mbase + lg*4;        // + r
    #pragma unroll
    for (int nt=0;nt<4;nt++){
        int n = n0 + nt*16 + li;
        if (n < 1024){
            int dir = n>>9, n2 = n&511;
            int q = n2>>7, cc = n2&127, w5 = cc>>4, li5 = cc&15;
            float sc = (q==2) ? 2.0f*LOG2E : LOG2E;
            #pragma unroll
            for (int r=0;r<4;r++){
                int m = mrow + r;
                int b = m&31, s = m>>5;
                int bg = b>>2, rb = b&3;
                gpre4[((size_t)((dir*8+bg)*256 + s)*8 + w5)*256 + (rb*16 + li5)*4 + q] = acc[nt][r]*sc;
            }
        } else if (n < 1152){
            int c = n - 1024;
            float bb = sentBc[c];
            #pragma unroll
            for (int r=0;r<4;r++){
                int m = mrow + r;
                int b = m&31, s = m>>5;
                sent_h[((size_t)(b*256+s))*128 + c] = tanh_f(acc[nt][r] + bb);
            }
        } else if (n < 1184){
            int c = n - 1152;
            #pragma unroll
            for (int r=0;r<4;r++){
                int m = mrow + r;
                int b = m&31, s = m>>5;
                lab_e[((size_t)(b*256+s))*32 + c] = acc[nt][r] * invn[m];
            }
        }
    }
}

// ---------------- k2: conv(K=3)+relu+max over L -> masked exp ----------------
__global__ __launch_bounds__(256) void k2_conv(const float* __restrict__ lab_e,
                        const float* __restrict__ convWc, const float* __restrict__ convBc,
                        const int* __restrict__ lens, float* __restrict__ e_ws){
    int b = blockIdx.x, stile = blockIdx.y, t = threadIdx.x;
    int sl = t>>3, oq = t&7;
    int s = stile*32 + sl;
    __shared__ float le_s[34*33];     // rows s0-1..s0+32, padded stride 33
    __shared__ float wle[LL*LL*3];
    __shared__ float wb[LL];
    int s0 = stile*32;
    for (int i=t; i<34*32; i+=256){
        int row = i>>5, col = i&31;
        int sg = s0 - 1 + row;
        le_s[row*33 + col] = (sg>=0 && sg<SS) ? lab_e[(size_t)b*SS*LL + sg*LL + col] : 0.f;
    }
    for (int i=t; i<LL*LL*3; i+=256) wle[i] = convWc[i];
    if (t < LL) wb[t] = convBc[t];
    __syncthreads();
    float lm = 0.f;   // relu >= 0
    #pragma unroll
    for (int op=0; op<4; op++){
        int o = oq*4 + op;
        float a0 = wb[o], a1 = 0.f, a2 = 0.f;
        #pragma unroll
        for (int i=0;i<LL;i++){
            a0 = fmaf(le_s[(sl+0)*33+i], wle[o*96 + i*3    ], a0);
            a1 = fmaf(le_s[(sl+1)*33+i], wle[o*96 + i*3 + 1], a1);
            a2 = fmaf(le_s[(sl+2)*33+i], wle[o*96 + i*3 + 2], a2);
        }
        lm = fmaxf(lm, fmaxf(a0+a1+a2, 0.f));
    }
    #pragma unroll
    for (int mk=1; mk<8; mk<<=1) lm = fmaxf(lm, __shfl_xor(lm, mk));
    if (oq == 0) e_ws[b*SS + s] = (s < lens[b]) ? __expf(lm) : 0.f;
}

// ---------------- k3: attention + sent_rep + cpart (fused, one block per b) ----------------
__global__ void k3_attn(const float* __restrict__ e_ws, const float* __restrict__ sent_h,
                        const float* __restrict__ Wfc, const float* __restrict__ Wbc,
                        const float* __restrict__ bfc, const float* __restrict__ bbc,
                        float* __restrict__ cpart){
    int b = blockIdx.x, t = threadIdx.x; // 256
    __shared__ float es[SS], red[SS], srp[2][GG], srs[GG];
    float ev = e_ws[b*SS + t];
    es[t]=ev; red[t]=ev; __syncthreads();
    for (int off=128; off>0; off>>=1){ if (t<off) red[t]+=red[t+off]; __syncthreads(); }
    float inv = 1.0f/red[0];
    int col = t&127, sh = t>>7;
    float a0 = 0.f, a1 = 0.f;
    int sb = sh*128;
    for (int s2=sb; s2<sb+128; s2+=2){
        a0 = fmaf(es[s2],   sent_h[((size_t)b*SS + s2)*GG + col], a0);
        a1 = fmaf(es[s2+1], sent_h[((size_t)b*SS + s2+1)*GG + col], a1);
    }
    srp[sh][col] = a0+a1;
    __syncthreads();
    if (t < GG) srs[t] = (srp[0][t]+srp[1][t])*inv;
    __syncthreads();
    #pragma unroll
    for (int chunk=0; chunk<4; chunk++){
        int ng = chunk*256 + t;          // 0..1023
        int dir = ng>>9, n = ng&511;
        const float* W = dir ? Wbc : Wfc;
        float c0 = (dir ? bbc : bfc)[n], c1 = 0.f;
        for (int g=0; g<GG; g+=2){
            c0 = fmaf(srs[g],   W[(size_t)(DD+g)*NG + n], c0);
            c1 = fmaf(srs[g+1], W[(size_t)(DD+g+1)*NG + n], c1);
        }
        cpart[((size_t)dir*NG + n)*BB + b] = c0+c1;
    }
}

// ---------------- K5: bidir LSTM, 16 wgs, 1 cell/lane, predicated A-read ----------------
// A-tile rows 1-3,5-7,9-11,13-15 are permanent zeros: only lanes with li%4==0
// read LDS (16 active lanes, 256B/instr); others keep zero fragments (exact).
__global__ __launch_bounds__(512,2) void k5_lstm(const float* __restrict__ gpre4,
                       const float* __restrict__ Ufc, const float* __restrict__ Ubc,
                       const float* __restrict__ cpart,
                       const int* __restrict__ lens, float* __restrict__ feat){
    int dir = blockIdx.x>>3, bg = blockIdx.x&7;
    int t = threadIdx.x;
    int w = t>>6, l = t&63, lg = l>>4, li = l&15;
    int j = w*16 + li;                         // hidden column 0..127
    int b = bg*4 + lg;                         // this lane's batch
    const float* Uc = dir ? Ubc : Ufc;

    short8 bfr[4][4];
    #pragma unroll
    for (int q=0;q<4;q++){
        float sc = (q==2) ? 2.0f*LOG2E : LOG2E;
        #pragma unroll
        for (int ks=0;ks<4;ks++){
            int n = q*128 + j;
            short8 v;
            #pragma unroll
            for (int jj=0;jj<8;jj++)
                v[jj] = (short)f2bf(Uc[(size_t)(ks*32 + lg*8 + jj)*NG + n] * sc);
            bfr[q][ks] = v;
        }
    }
    float cpr[4];
    #pragma unroll
    for (int q=0;q<4;q++)
        cpr[q] = cpart[((size_t)(dir*NG + q*128 + j))*BB + b] * ((q==2) ? 2.0f*LOG2E : LOG2E);
    int len1 = lens[b];

    __shared__ u16 Hhi[2][16*128];   // XOR-swizzled, double-buffered
    for (int i=t; i<2*2048; i+=512) ((u16*)Hhi)[i] = 0;

    bool rdp = ((li & 3) == 0);      // only 16 lanes/wave read the A tile
    int roff[4];
    #pragma unroll
    for (int ks=0;ks<4;ks++)
        roff[ks] = (li*256 + ((ks*64 + lg*16) ^ ((li&7)<<4))) >> 1;
    int woff;
    { int row = lg*4; woff = (row*256 + ((2*j) ^ ((row&7)<<4))) >> 1; }

    float c = 0.f, h = 0.f;
    int sgn = dir ? -1 : 1;
    int s0 = dir ? (SS-1) : 0;
    const float* gl = gpre4 + ((size_t)(dir*8 + bg)*256 + s0)*2048 + w*256 + l*4;
    ptrdiff_t gstep = (ptrdiff_t)sgn * 2048;

    f32x4 gA = *(const f32x4*)gl;
    f32x4 gB = *(const f32x4*)(gl + gstep);
    const float* glp = gl + 2*gstep;

    float* fb = feat + ((size_t)b*SS + s0)*256 + dir*128 + j;
    ptrdiff_t fstep = (ptrdiff_t)sgn * 256;

    int s = s0;
    __syncthreads();

#define K5_STEP(P, G)                                                          \
    {                                                                          \
        short8 ah[4];                                                          \
        _Pragma("unroll")                                                      \
        for (int ks=0;ks<4;ks++){                                              \
            short8 a;                                                          \
            _Pragma("unroll")                                                  \
            for (int jj=0;jj<8;jj++) a[jj] = 0;                                \
            if (rdp) a = *(const short8*)&Hhi[P][roff[ks]];                    \
            ah[ks] = a;                                                        \
        }                                                                      \
        f32x4 acA[4], acB[4];                                                  \
        _Pragma("unroll")                                                      \
        for (int q=0;q<4;q++){                                                 \
            f32x4 z; z[0]=G[q]+cpr[q]; z[1]=0.f; z[2]=0.f; z[3]=0.f; acA[q]=z; \
            f32x4 z2; z2[0]=0.f; z2[1]=0.f; z2[2]=0.f; z2[3]=0.f; acB[q]=z2;   \
        }                                                                      \
        if (tt2 + 2 < SS){ G = *(const f32x4*)glp; glp += gstep; }             \
        _Pragma("unroll")                                                      \
        for (int q=0;q<4;q++){                                                 \
            acA[q] = __builtin_amdgcn_mfma_f32_16x16x32_bf16(ah[0], bfr[q][0], acA[q], 0,0,0); \
            acB[q] = __builtin_amdgcn_mfma_f32_16x16x32_bf16(ah[2], bfr[q][2], acB[q], 0,0,0); \
            acA[q] = __builtin_amdgcn_mfma_f32_16x16x32_bf16(ah[1], bfr[q][1], acA[q], 0,0,0); \
            acB[q] = __builtin_amdgcn_mfma_f32_16x16x32_bf16(ah[3], bfr[q][3], acB[q], 0,0,0); \
        }                                                                      \
        float xg0 = acA[0][0] + acB[0][0];                                     \
        float xg1 = acA[1][0] + acB[1][0];                                     \
        float xg2 = acA[2][0] + acB[2][0];                                     \
        float xg3 = acA[3][0] + acB[3][0];                                     \
        float si = rcp_f(1.0f + exp2_f(-xg0));                                 \
        float sf = rcp_f(1.0f + exp2_f(-xg1));                                 \
        float tg = 1.0f - 2.0f*rcp_f(exp2_f(xg2) + 1.0f);                      \
        float so = rcp_f(1.0f + exp2_f(-xg3));                                 \
        float cn = sf*c + si*tg;                                               \
        float th = 1.0f - 2.0f*rcp_f(exp2_f(cn*(2.0f*LOG2E)) + 1.0f);          \
        float hn = so*th;                                                      \
        if (s < 128){ c = cn; h = hn; fb[0] = hn; }                            \
        else { bool mm = (s < len1); c = mm?cn:c; h = mm?hn:h; fb[0] = mm?hn:0.f; } \
        Hhi[P^1][woff] = f2bf(h);                                              \
        asm volatile("s_waitcnt lgkmcnt(0)" ::: "memory");                     \
        __builtin_amdgcn_sched_barrier(0);                                     \
        __builtin_amdgcn_s_barrier();                                          \
        __builtin_amdgcn_sched_barrier(0);                                     \
        s += sgn; fb += fstep;                                                 \
    }

    for (int tt=0; tt<SS; tt+=2){
        { int tt2 = tt;   K5_STEP(0, gA) }
        { int tt2 = tt+1; K5_STEP(1, gB) }
    }
#undef K5_STEP
}

// ---------------- k6: tag/mem projections + blend ----------------
__global__ void k6_final(const float* __restrict__ feat, const int* __restrict__ wid,
                         const int* __restrict__ lens,
                         const u16* __restrict__ tagWT, const float* __restrict__ tagBc,
                         const u16* __restrict__ memWT, const float* __restrict__ memBc,
                         const void* __restrict__ bank, const int* __restrict__ flags,
                         void* __restrict__ out){
    int t = threadIdx.x;
    int tok = blockIdx.x*8 + (t>>5);
    int lcol = t&31;
    int b = tok>>8, s = tok&255;
    int f32m = flags[0];
    int idx = wid[tok];
    bool m = s < lens[b];
    const float* fr = feat + (size_t)tok*256;
    float a0 = tagBc[lcol], a1=0.f, a2=0.f, a3=0.f;
    #pragma unroll 4
    for (int cc=0; cc<32; cc++){
        short8 tw = *(const short8*)&tagWT[lcol*256 + cc*8];
        a0 = fmaf(fr[cc*8+0], bf2f((u16)tw[0]), a0);
        a1 = fmaf(fr[cc*8+1], bf2f((u16)tw[1]), a1);
        a2 = fmaf(fr[cc*8+2], bf2f((u16)tw[2]), a2);
        a3 = fmaf(fr[cc*8+3], bf2f((u16)tw[3]), a3);
        a0 = fmaf(fr[cc*8+4], bf2f((u16)tw[4]), a0);
        a1 = fmaf(fr[cc*8+5], bf2f((u16)tw[5]), a1);
        a2 = fmaf(fr[cc*8+6], bf2f((u16)tw[6]), a2);
        a3 = fmaf(fr[cc*8+7], bf2f((u16)tw[7]), a3);
    }
    float r1 = (a0+a1)+(a2+a3);
    float b0 = memBc[lcol], b1=0.f, b2=0.f, b3=0.f;
    if (m){
        if (f32m){
            const float* br = (const float*)bank + (size_t)idx*256;
            #pragma unroll 4
            for (int cc=0; cc<32; cc++){
                short8 tw = *(const short8*)&memWT[lcol*256 + cc*8];
                b0 = fmaf(br[cc*8+0], bf2f((u16)tw[0]), b0);
                b1 = fmaf(br[cc*8+1], bf2f((u16)tw[1]), b1);
                b2 = fmaf(br[cc*8+2], bf2f((u16)tw[2]), b2);
                b3 = fmaf(br[cc*8+3], bf2f((u16)tw[3]), b3);
                b0 = fmaf(br[cc*8+4], bf2f((u16)tw[4]), b0);
                b1 = fmaf(br[cc*8+5], bf2f((u16)tw[5]), b1);
                b2 = fmaf(br[cc*8+6], bf2f((u16)tw[6]), b2);
                b3 = fmaf(br[cc*8+7], bf2f((u16)tw[7]), b3);
            }
        } else {
            const u16* br = (const u16*)bank + (size_t)idx*256;
            #pragma unroll 4
            for (int cc=0; cc<32; cc++){
                short8 tw = *(const short8*)&memWT[lcol*256 + cc*8];
                short8 bv = *(const short8*)&br[cc*8];
                b0 = fmaf(bf2f((u16)bv[0]), bf2f((u16)tw[0]), b0);
                b1 = fmaf(bf2f((u16)bv[1]), bf2f((u16)tw[1]), b1);
                b2 = fmaf(bf2f((u16)bv[2]), bf2f((u16)tw[2]), b2);
                b3 = fmaf(bf2f((u16)bv[3]), bf2f((u16)tw[3]), b3);
                b0 = fmaf(bf2f((u16)bv[4]), bf2f((u16)tw[4]), b0);
                b1 = fmaf(bf2f((u16)bv[5]), bf2f((u16)tw[5]), b1);
                b2 = fmaf(bf2f((u16)bv[6]), bf2f((u16)tw[6]), b2);
                b3 = fmaf(bf2f((u16)bv[7]), bf2f((u16)tw[7]), b3);
            }
        }
    }
    float r2 = (b0+b1)+(b2+b3);
    float res = 0.5f*r1 + 0.5f*r2;
    if (f32m) ((float*)out)[(size_t)tok*LL + lcol] = res;
    else      ((u16*)out)[(size_t)tok*LL + lcol]   = f2bf(res);
}

extern "C" void kernel_launch(void* const* d_in, const int* in_sizes, int n_in,
                              void* d_out, int out_size, void* d_ws, size_t ws_size,
                              hipStream_t stream){
    const int* wid  = (const int*)d_in[0];
    const int* lens = (const int*)d_in[1];
    // d_in[2..6]: char_*, mask, idx_inputs — unused (mask recomputed from lens)

    char* ws = (char*)d_ws;
    int*   flags  = (int*)  (ws + 0);
    float* can    = (float*)(ws + 1024);        // 1.74 MB canonical f32 weights
    u16*   WcatT  = (u16*)  (ws + 1900544);     // 1216x128 bf16 = 304 KB
    u16*   tagWT  = (u16*)  (ws + 2211840);     // 16 KB
    u16*   memWT  = (u16*)  (ws + 2228224);     // 16 KB
    float* invn   = (float*)(ws + 2244608);     // 32 KB
    float* cpart  = (float*)(ws + 2277376);     // 128 KB [dir][n][b]
    float* e_ws   = (float*)(ws + 2408448);     // 32 KB
    u16*   weC    = (u16*)  (ws + 4194304);     // 2 MB  [m=s*32+b][128] bf16
    float* lab_e  = (float*)(ws + 8388608);     // 1 MB
    float* sent_h = (float*)(ws + 9437184);     // 4 MB
    float* gpre4  = (float*)(ws + 16777216);    // 32 MiB (pre-scaled, K5 layout)
    float* feat   = (float*)(ws + 50331648);    // 8 MB  [b][s][256]

    // canonical sub-offsets (elements)
    float* sentBc = can + 20480;
    float* convWc = can + 20608;
    float* convBc = can + 23680;
    float* Wfc    = can + 23712;
    float* Wbc    = can + 154784;
    float* bfc    = can + 285856;
    float* bbc    = can + 286368;
    float* Ufc    = can + 286880;
    float* Ubc    = can + 352416;
    float* tagBc  = can + 426144;
    float* memBc  = can + 434368;

    static const int cn_n[15]   = {4096,16384,128,3072,32,131072,131072,512,512,65536,65536,8192,32,8192,32};
    static const int cn_src[15] = {8,9,10,11,12,13,16,15,18,14,17,19,20,21,22};
    PJobs jb;
    {
        int off = 0;
        for (int i=0;i<15;i++){
            jb.src[i]=d_in[cn_src[i]]; jb.n[i]=cn_n[i]; jb.p0[i]=off; jb.p1[i]=0; jb.type[i]=0;
            off+=cn_n[i];
        }
        jb.src[15]=d_in[13]; jb.n[15]=65536; jb.p0[15]=0;    jb.p1[15]=512; jb.type[15]=1; // Wf[:128]
        jb.src[16]=d_in[16]; jb.n[16]=65536; jb.p0[16]=512;  jb.p1[16]=512; jb.type[16]=1; // Wb[:128]
        jb.src[17]=d_in[9];  jb.n[17]=16384; jb.p0[17]=1024; jb.p1[17]=128; jb.type[17]=1; // sentW
        jb.src[18]=d_in[19]; jb.n[18]=8192;  jb.p0[18]=0;    jb.p1[18]=0;   jb.type[18]=2;
        jb.src[19]=d_in[21]; jb.n[19]=8192;  jb.p0[19]=1;    jb.p1[19]=0;   jb.type[19]=2;
        jb.src[20]=d_in[8];  jb.n[20]=4096;  jb.p0[20]=0;    jb.p1[20]=0;   jb.type[20]=3; // label norm
    }

    kprep  <<<dim3(512,21), 256, 0, stream>>>(jb, d_in[7], flags, can, WcatT, tagWT, memWT);
    k1_token<<<8192, 128, 0, stream>>>(wid, d_in[7], flags, weC, invn);
    kgemm  <<<dim3(128,19), 256, 0, stream>>>(weC, WcatT, invn, sentBc, gpre4, sent_h, lab_e);
    k2_conv<<<dim3(32,8), 256, 0, stream>>>(lab_e, convWc, convBc, lens, e_ws);
    k3_attn<<<32, 256, 0, stream>>>(e_ws, sent_h, Wfc, Wbc, bfc, bbc, cpart);
    k5_lstm<<<16, 512, 0, stream>>>(gpre4, Ufc, Ubc, cpart, lens, feat);
    k6_final<<<1024, 256, 0, stream>>>(feat, wid, lens, tagWT, tagBc, memWT, memBc,
                                       d_in[23], flags, d_out);
}

// Round 8
// 241.160 us; speedup vs baseline: 1.5084x; 1.5084x over previous
//
#include <hip/hip_runtime.h>
#include <hip/hip_bf16.h>

#define BB 32
#define SS 256
#define DD 128
#define GG 128
#define NG 512   // 4*(H/2) gate columns per direction
#define LL 32
#define LOG2E 1.4426950408889634f

typedef unsigned short u16;
typedef __attribute__((ext_vector_type(8))) short short8;
typedef __attribute__((ext_vector_type(4))) float f32x4;

__device__ __forceinline__ float bf2f(u16 u){ return __uint_as_float(((unsigned)u)<<16); }
__device__ __forceinline__ u16 f2bf(float f){
    unsigned x = __float_as_uint(f);
    unsigned r = x + 0x7fffu + ((x>>16)&1u);
    return (u16)(r>>16);
}
__device__ __forceinline__ float tanh_f(float x){ float e=__expf(2.0f*x); return 1.0f - 2.0f/(e+1.0f); }

__device__ __forceinline__ float exp2_f(float x){
#if __has_builtin(__builtin_amdgcn_exp2f)
    return __builtin_amdgcn_exp2f(x);
#elif __has_builtin(__builtin_amdgcn_expf)
    return __builtin_amdgcn_expf(x);
#else
    return __expf(x * 0.6931471805599453f);
#endif
}
__device__ __forceinline__ float rcp_f(float x){
#if __has_builtin(__builtin_amdgcn_rcpf)
    return __builtin_amdgcn_rcpf(x);
#else
    return 1.0f / x;
#endif
}

// ---------------- kprep: per-block dtype flag + canonicalize + transposes + label-norm ----------------
struct PJobs { const void* src[21]; int n[21]; int p0[21]; int p1[21]; int type[21]; };

__global__ void kprep(PJobs jb, const void* __restrict__ wemb, int* __restrict__ flags,
                      float* __restrict__ can,
                      u16* __restrict__ WcatT, u16* __restrict__ tagWT, u16* __restrict__ memWT){
    int t = threadIdx.x;
    __shared__ int cw[4];
    __shared__ int sflag;
    {
        u16 v = ((const u16*)wemb)[2*t];
        int e = (v>>7)&0xFF;
        int c = (e>=0x90)?1:0;
        #pragma unroll
        for (int mk=32; mk>0; mk>>=1) c += __shfl_xor(c, mk);
        if ((t&63)==0) cw[t>>6] = c;
        __syncthreads();
        if (t==0) sflag = (cw[0]+cw[1]+cw[2]+cw[3] >= 32) ? 1 : 0;
        __syncthreads();
    }
    int f = sflag;
    if (blockIdx.x==0 && blockIdx.y==0 && t==0) flags[0] = f;

    int id = blockIdx.y;
    int i = blockIdx.x*256 + t;
    if (i >= jb.n[id]) return;
    const void* src = jb.src[id];
    int p0 = jb.p0[id];
    int ty = jb.type[id];
    if (ty == 0){
        float v = f ? ((const float*)src)[i] : bf2f(((const u16*)src)[i]);
        can[p0 + i] = v;
    } else if (ty == 1){
        int c = i>>7, k = i&127;
        float v = f ? ((const float*)src)[k*jb.p1[id] + c] : bf2f(((const u16*)src)[k*jb.p1[id] + c]);
        WcatT[(size_t)(p0 + c)*128 + k] = f2bf(v);
    } else if (ty == 2){
        int l = i&31, k = i>>5;
        float v = f ? ((const float*)src)[k*32 + l] : bf2f(((const u16*)src)[k*32 + l]);
        (p0 ? memWT : tagWT)[l*256 + k] = f2bf(v);
    } else {
        int row = i>>7, col = i&127;
        float v = f ? ((const float*)src)[i] : bf2f(((const u16*)src)[i]);
        float sq = v*v;
        #pragma unroll
        for (int mk=32; mk>0; mk>>=1) sq += __shfl_xor(sq, mk);
        __shared__ float r4[4];
        if ((t&63)==0) r4[t>>6] = sq;
        __syncthreads();
        int half = t>>7;
        float tot = r4[half*2] + r4[half*2+1];
        float inv = 1.0f/(sqrtf(tot) + 1e-8f);
        WcatT[(size_t)(1152+row)*128 + col] = f2bf(v*inv);
        WcatT[(size_t)(1184+row)*128 + col] = 0;   // pad cols
    }
}

// ---------------- k1: gather + norm -> weC (bf16), invn ----------------
__global__ void k1_token(const int* __restrict__ wid, const void* __restrict__ wemb,
                         const int* __restrict__ flags,
                         u16* __restrict__ weC, float* __restrict__ invn){
    int blk = blockIdx.x;          // b*256+s
    int t = threadIdx.x;           // 128
    int idx = wid[blk];
    float wv = flags[0] ? ((const float*)wemb)[(size_t)idx*DD + t]
                        : bf2f(((const u16*)wemb)[(size_t)idx*DD + t]);
    int b = blk>>8, s = blk&255;
    int m = s*BB + b;
    weC[(size_t)m*DD + t] = f2bf(wv);
    float sq = wv*wv;
    #pragma unroll
    for (int mk=32; mk>0; mk>>=1) sq += __shfl_xor(sq, mk);
    __shared__ float red2[2];
    if ((t&63)==0) red2[t>>6] = sq;
    __syncthreads();
    if (t==0) invn[m] = 1.0f/(sqrtf(red2[0]+red2[1]) + 1e-8f);
}

// ---------------- kgemm: [gpre4 | sent_h | lab_e] = weC(bf16) @ WcatT(bf16), MFMA ----------------
__global__ __launch_bounds__(256) void kgemm(const u16* __restrict__ weC,
                      const u16* __restrict__ WcatT,
                      const float* __restrict__ invn, const float* __restrict__ sentBc,
                      float* __restrict__ gpre4, float* __restrict__ sent_h,
                      float* __restrict__ lab_e){
    int mt = blockIdx.x;            // 0..127
    int nb = blockIdx.y;            // 0..18
    int t = threadIdx.x;
    int w4 = t>>6, l = t&63, li = l&15, lg = l>>4;
    int mbase = mt*64 + w4*16;
    int n0 = nb*64;
    short8 af[4];
    #pragma unroll
    for (int ks=0;ks<4;ks++)
        af[ks] = *(const short8*)&weC[(size_t)(mbase + li)*128 + ks*32 + lg*8];
    f32x4 acc[4];
    #pragma unroll
    for (int nt=0;nt<4;nt++){
        short8 bf[4];
        #pragma unroll
        for (int ks=0;ks<4;ks++)
            bf[ks] = *(const short8*)&WcatT[(size_t)(n0 + nt*16 + li)*128 + ks*32 + lg*8];
        f32x4 a; a[0]=0.f; a[1]=0.f; a[2]=0.f; a[3]=0.f;
        #pragma unroll
        for (int ks=0;ks<4;ks++)
            a = __builtin_amdgcn_mfma_f32_16x16x32_bf16(af[ks], bf[ks], a, 0,0,0);
        acc[nt] = a;
    }
    int mrow = mbase + lg*4;        // + r
    #pragma unroll
    for (int nt=0;nt<4;nt++){
        int n = n0 + nt*16 + li;
        if (n < 1024){
            int dir = n>>9, n2 = n&511;
            int q = n2>>7, cc = n2&127, w5 = cc>>4, li5 = cc&15;
            float sc = (q==2) ? 2.0f*LOG2E : LOG2E;
            #pragma unroll
            for (int r=0;r<4;r++){
                int m = mrow + r;
                int b = m&31, s = m>>5;
                int bg = b>>2, rb = b&3;
                gpre4[((size_t)((dir*8+bg)*256 + s)*8 + w5)*256 + (rb*16 + li5)*4 + q] = acc[nt][r]*sc;
            }
        } else if (n < 1152){
            int c = n - 1024;
            float bb = sentBc[c];
            #pragma unroll
            for (int r=0;r<4;r++){
                int m = mrow + r;
                int b = m&31, s = m>>5;
                sent_h[((size_t)(b*256+s))*128 + c] = tanh_f(acc[nt][r] + bb);
            }
        } else if (n < 1184){
            int c = n - 1152;
            #pragma unroll
            for (int r=0;r<4;r++){
                int m = mrow + r;
                int b = m&31, s = m>>5;
                lab_e[((size_t)(b*256+s))*32 + c] = acc[nt][r] * invn[m];
            }
        }
    }
}

// ---------------- k2: conv(K=3)+relu+max over L -> masked exp ----------------
__global__ __launch_bounds__(256) void k2_conv(const float* __restrict__ lab_e,
                        const float* __restrict__ convWc, const float* __restrict__ convBc,
                        const int* __restrict__ lens, float* __restrict__ e_ws){
    int b = blockIdx.x, stile = blockIdx.y, t = threadIdx.x;
    int sl = t>>3, oq = t&7;
    int s = stile*32 + sl;
    __shared__ float le_s[34*33];     // rows s0-1..s0+32, padded stride 33
    __shared__ float wle[LL*LL*3];
    __shared__ float wb[LL];
    int s0 = stile*32;
    for (int i=t; i<34*32; i+=256){
        int row = i>>5, col = i&31;
        int sg = s0 - 1 + row;
        le_s[row*33 + col] = (sg>=0 && sg<SS) ? lab_e[(size_t)b*SS*LL + sg*LL + col] : 0.f;
    }
    for (int i=t; i<LL*LL*3; i+=256) wle[i] = convWc[i];
    if (t < LL) wb[t] = convBc[t];
    __syncthreads();
    float lm = 0.f;   // relu >= 0
    #pragma unroll
    for (int op=0; op<4; op++){
        int o = oq*4 + op;
        float a0 = wb[o], a1 = 0.f, a2 = 0.f;
        #pragma unroll
        for (int i=0;i<LL;i++){
            a0 = fmaf(le_s[(sl+0)*33+i], wle[o*96 + i*3    ], a0);
            a1 = fmaf(le_s[(sl+1)*33+i], wle[o*96 + i*3 + 1], a1);
            a2 = fmaf(le_s[(sl+2)*33+i], wle[o*96 + i*3 + 2], a2);
        }
        lm = fmaxf(lm, fmaxf(a0+a1+a2, 0.f));
    }
    #pragma unroll
    for (int mk=1; mk<8; mk<<=1) lm = fmaxf(lm, __shfl_xor(lm, mk));
    if (oq == 0) e_ws[b*SS + s] = (s < lens[b]) ? __expf(lm) : 0.f;
}

// ---------------- k3a: partial attention sums over 32-s tiles (256 blocks) ----------------
__global__ void k3a_attn(const float* __restrict__ e_ws, const float* __restrict__ sent_h,
                         float* __restrict__ srp, float* __restrict__ esum_p){
    int b = blockIdx.x, st = blockIdx.y, t = threadIdx.x;  // 32 x 8, 256 thr
    int col = t&127, sh = t>>7;
    __shared__ float es[32];
    __shared__ float red[2][GG];
    if (t < 32) es[t] = e_ws[b*SS + st*32 + t];
    __syncthreads();
    int sb = st*32 + sh*16;
    float a0 = 0.f, a1 = 0.f;
    #pragma unroll
    for (int s2=0; s2<16; s2+=2){
        a0 = fmaf(es[sh*16+s2],   sent_h[((size_t)b*SS + sb+s2)*GG + col], a0);
        a1 = fmaf(es[sh*16+s2+1], sent_h[((size_t)b*SS + sb+s2+1)*GG + col], a1);
    }
    red[sh][col] = a0+a1;
    __syncthreads();
    if (t < GG) srp[((size_t)b*8 + st)*GG + t] = red[0][t] + red[1][t];
    if (t < 32){
        float e = es[t];
        #pragma unroll
        for (int mk=16; mk>0; mk>>=1) e += __shfl_xor(e, mk);
        if (t==0) esum_p[b*8 + st] = e;
    }
}

// ---------------- k3b: combine partials + cpart matvec (128 blocks) ----------------
__global__ void k3b_cpart(const float* __restrict__ srp, const float* __restrict__ esum_p,
                          const float* __restrict__ Wfc, const float* __restrict__ Wbc,
                          const float* __restrict__ bfc, const float* __restrict__ bbc,
                          float* __restrict__ cpart){
    int chunk = blockIdx.x, b = blockIdx.y, t = threadIdx.x;  // 4 x 32, 256 thr
    __shared__ float srs[GG];
    if (t < GG){
        float a = 0.f;
        #pragma unroll
        for (int st=0; st<8; st++) a += srp[((size_t)b*8 + st)*GG + t];
        float es = 0.f;
        #pragma unroll
        for (int st=0; st<8; st++) es += esum_p[b*8 + st];
        srs[t] = a * (1.0f/es);
    }
    __syncthreads();
    int ng = chunk*256 + t;          // 0..1023
    int dir = ng>>9, n = ng&511;
    const float* W = dir ? Wbc : Wfc;
    float c0 = (dir ? bbc : bfc)[n], c1 = 0.f;
    for (int g=0; g<GG; g+=2){
        c0 = fmaf(srs[g],   W[(size_t)(DD+g)*NG + n], c0);
        c1 = fmaf(srs[g+1], W[(size_t)(DD+g+1)*NG + n], c1);
    }
    cpart[((size_t)dir*NG + n)*BB + b] = c0+c1;
}

// ---------------- K5: bidir LSTM, 16 wgs, 1 cell/lane, hoisted-zero predicated A-read ----------------
// A-tile rows != 0 mod 4 are permanent zeros. Fragments zero-initialized ONCE;
// per-step exec-masked ds_read (li%4==0 lanes) overwrites active lanes only —
// inactive lanes keep zeros with NO per-step v_mov cost.
__global__ __launch_bounds__(512) void k5_lstm(const float* __restrict__ gpre4,
                       const float* __restrict__ Ufc, const float* __restrict__ Ubc,
                       const float* __restrict__ cpart,
                       const int* __restrict__ lens, float* __restrict__ feat){
    int dir = blockIdx.x>>3, bg = blockIdx.x&7;
    int t = threadIdx.x;
    int w = t>>6, l = t&63, lg = l>>4, li = l&15;
    int j = w*16 + li;                         // hidden column 0..127
    int b = bg*4 + lg;                         // this lane's batch
    const float* Uc = dir ? Ubc : Ufc;

    short8 bfr[4][4];
    #pragma unroll
    for (int q=0;q<4;q++){
        float sc = (q==2) ? 2.0f*LOG2E : LOG2E;
        #pragma unroll
        for (int ks=0;ks<4;ks++){
            int n = q*128 + j;
            short8 v;
            #pragma unroll
            for (int jj=0;jj<8;jj++)
                v[jj] = (short)f2bf(Uc[(size_t)(ks*32 + lg*8 + jj)*NG + n] * sc);
            bfr[q][ks] = v;
        }
    }
    float cpr[4];
    #pragma unroll
    for (int q=0;q<4;q++)
        cpr[q] = cpart[((size_t)(dir*NG + q*128 + j))*BB + b] * ((q==2) ? 2.0f*LOG2E : LOG2E);
    int len1 = lens[b];

    __shared__ u16 Hhi[2][16*128];   // XOR-swizzled, double-buffered
    for (int i=t; i<2*2048; i+=512) ((u16*)Hhi)[i] = 0;

    bool rdp = ((li & 3) == 0);      // only 16 lanes/wave read the A tile
    int roff[4];
    #pragma unroll
    for (int ks=0;ks<4;ks++)
        roff[ks] = (li*256 + ((ks*64 + lg*16) ^ ((li&7)<<4))) >> 1;
    int woff;
    { int row = lg*4; woff = (row*256 + ((2*j) ^ ((row&7)<<4))) >> 1; }

    // A-fragments: zero once; predicated loads preserve inactive lanes' zeros
    short8 ah[4];
    #pragma unroll
    for (int ks=0;ks<4;ks++){
        #pragma unroll
        for (int jj=0;jj<8;jj++) ah[ks][jj] = 0;
    }

    float c = 0.f, h = 0.f;
    int sgn = dir ? -1 : 1;
    int s0 = dir ? (SS-1) : 0;
    const float* gl = gpre4 + ((size_t)(dir*8 + bg)*256 + s0)*2048 + w*256 + l*4;
    ptrdiff_t gstep = (ptrdiff_t)sgn * 2048;

    f32x4 gA = *(const f32x4*)gl;
    f32x4 gB = *(const f32x4*)(gl + gstep);
    const float* glp = gl + 2*gstep;

    float* fb = feat + ((size_t)b*SS + s0)*256 + dir*128 + j;
    ptrdiff_t fstep = (ptrdiff_t)sgn * 256;

    int s = s0;
    __syncthreads();

#define K5_STEP(P, G)                                                          \
    {                                                                          \
        if (rdp){                                                              \
            ah[0] = *(const short8*)&Hhi[P][roff[0]];                          \
            ah[1] = *(const short8*)&Hhi[P][roff[1]];                          \
            ah[2] = *(const short8*)&Hhi[P][roff[2]];                          \
            ah[3] = *(const short8*)&Hhi[P][roff[3]];                          \
        }                                                                      \
        f32x4 ac[4];                                                           \
        _Pragma("unroll")                                                      \
        for (int q=0;q<4;q++){ f32x4 z; z[0]=G[q]+cpr[q]; z[1]=0.f; z[2]=0.f; z[3]=0.f; ac[q]=z; } \
        if (tt2 + 2 < SS){ G = *(const f32x4*)glp; glp += gstep; }             \
        _Pragma("unroll")                                                      \
        for (int ks=0;ks<4;ks++){                                              \
            _Pragma("unroll")                                                  \
            for (int q=0;q<4;q++)                                              \
                ac[q] = __builtin_amdgcn_mfma_f32_16x16x32_bf16(ah[ks], bfr[q][ks], ac[q], 0,0,0); \
        }                                                                      \
        float si = rcp_f(1.0f + exp2_f(-ac[0][0]));                            \
        float sf = rcp_f(1.0f + exp2_f(-ac[1][0]));                            \
        float tg = 1.0f - 2.0f*rcp_f(exp2_f(ac[2][0]) + 1.0f);                 \
        float so = rcp_f(1.0f + exp2_f(-ac[3][0]));                            \
        float cn = sf*c + si*tg;                                               \
        float th = 1.0f - 2.0f*rcp_f(exp2_f(cn*(2.0f*LOG2E)) + 1.0f);          \
        float hn = so*th;                                                      \
        if (s < 128){ c = cn; h = hn; fb[0] = hn; }                            \
        else { bool mm = (s < len1); c = mm?cn:c; h = mm?hn:h; fb[0] = mm?hn:0.f; } \
        Hhi[P^1][woff] = f2bf(h);                                              \
        asm volatile("s_waitcnt lgkmcnt(0)" ::: "memory");                     \
        __builtin_amdgcn_sched_barrier(0);                                     \
        __builtin_amdgcn_s_barrier();                                          \
        __builtin_amdgcn_sched_barrier(0);                                     \
        s += sgn; fb += fstep;                                                 \
    }

    for (int tt=0; tt<SS; tt+=2){
        { int tt2 = tt;   K5_STEP(0, gA) }
        { int tt2 = tt+1; K5_STEP(1, gB) }
    }
#undef K5_STEP
}

// ---------------- k6: tag/mem projections + blend ----------------
__global__ void k6_final(const float* __restrict__ feat, const int* __restrict__ wid,
                         const int* __restrict__ lens,
                         const u16* __restrict__ tagWT, const float* __restrict__ tagBc,
                         const u16* __restrict__ memWT, const float* __restrict__ memBc,
                         const void* __restrict__ bank, const int* __restrict__ flags,
                         void* __restrict__ out){
    int t = threadIdx.x;
    int tok = blockIdx.x*8 + (t>>5);
    int lcol = t&31;
    int b = tok>>8, s = tok&255;
    int f32m = flags[0];
    int idx = wid[tok];
    bool m = s < lens[b];
    const float* fr = feat + (size_t)tok*256;
    float a0 = tagBc[lcol], a1=0.f, a2=0.f, a3=0.f;
    #pragma unroll 4
    for (int cc=0; cc<32; cc++){
        short8 tw = *(const short8*)&tagWT[lcol*256 + cc*8];
        a0 = fmaf(fr[cc*8+0], bf2f((u16)tw[0]), a0);
        a1 = fmaf(fr[cc*8+1], bf2f((u16)tw[1]), a1);
        a2 = fmaf(fr[cc*8+2], bf2f((u16)tw[2]), a2);
        a3 = fmaf(fr[cc*8+3], bf2f((u16)tw[3]), a3);
        a0 = fmaf(fr[cc*8+4], bf2f((u16)tw[4]), a0);
        a1 = fmaf(fr[cc*8+5], bf2f((u16)tw[5]), a1);
        a2 = fmaf(fr[cc*8+6], bf2f((u16)tw[6]), a2);
        a3 = fmaf(fr[cc*8+7], bf2f((u16)tw[7]), a3);
    }
    float r1 = (a0+a1)+(a2+a3);
    float b0 = memBc[lcol], b1=0.f, b2=0.f, b3=0.f;
    if (m){
        if (f32m){
            const float* br = (const float*)bank + (size_t)idx*256;
            #pragma unroll 4
            for (int cc=0; cc<32; cc++){
                short8 tw = *(const short8*)&memWT[lcol*256 + cc*8];
                b0 = fmaf(br[cc*8+0], bf2f((u16)tw[0]), b0);
                b1 = fmaf(br[cc*8+1], bf2f((u16)tw[1]), b1);
                b2 = fmaf(br[cc*8+2], bf2f((u16)tw[2]), b2);
                b3 = fmaf(br[cc*8+3], bf2f((u16)tw[3]), b3);
                b0 = fmaf(br[cc*8+4], bf2f((u16)tw[4]), b0);
                b1 = fmaf(br[cc*8+5], bf2f((u16)tw[5]), b1);
                b2 = fmaf(br[cc*8+6], bf2f((u16)tw[6]), b2);
                b3 = fmaf(br[cc*8+7], bf2f((u16)tw[7]), b3);
            }
        } else {
            const u16* br = (const u16*)bank + (size_t)idx*256;
            #pragma unroll 4
            for (int cc=0; cc<32; cc++){
                short8 tw = *(const short8*)&memWT[lcol*256 + cc*8];
                short8 bv = *(const short8*)&br[cc*8];
                b0 = fmaf(bf2f((u16)bv[0]), bf2f((u16)tw[0]), b0);
                b1 = fmaf(bf2f((u16)bv[1]), bf2f((u16)tw[1]), b1);
                b2 = fmaf(bf2f((u16)bv[2]), bf2f((u16)tw[2]), b2);
                b3 = fmaf(bf2f((u16)bv[3]), bf2f((u16)tw[3]), b3);
                b0 = fmaf(bf2f((u16)bv[4]), bf2f((u16)tw[4]), b0);
                b1 = fmaf(bf2f((u16)bv[5]), bf2f((u16)tw[5]), b1);
                b2 = fmaf(bf2f((u16)bv[6]), bf2f((u16)tw[6]), b2);
                b3 = fmaf(bf2f((u16)bv[7]), bf2f((u16)tw[7]), b3);
            }
        }
    }
    float r2 = (b0+b1)+(b2+b3);
    float res = 0.5f*r1 + 0.5f*r2;
    if (f32m) ((float*)out)[(size_t)tok*LL + lcol] = res;
    else      ((u16*)out)[(size_t)tok*LL + lcol]   = f2bf(res);
}

extern "C" void kernel_launch(void* const* d_in, const int* in_sizes, int n_in,
                              void* d_out, int out_size, void* d_ws, size_t ws_size,
                              hipStream_t stream){
    const int* wid  = (const int*)d_in[0];
    const int* lens = (const int*)d_in[1];
    // d_in[2..6]: char_*, mask, idx_inputs — unused (mask recomputed from lens)

    char* ws = (char*)d_ws;
    int*   flags  = (int*)  (ws + 0);
    float* can    = (float*)(ws + 1024);        // 1.74 MB canonical f32 weights
    u16*   WcatT  = (u16*)  (ws + 1900544);     // 1216x128 bf16 = 304 KB
    u16*   tagWT  = (u16*)  (ws + 2211840);     // 16 KB
    u16*   memWT  = (u16*)  (ws + 2228224);     // 16 KB
    float* invn   = (float*)(ws + 2244608);     // 32 KB
    float* cpart  = (float*)(ws + 2277376);     // 128 KB [dir][n][b]
    float* e_ws   = (float*)(ws + 2408448);     // 32 KB
    float* srp    = (float*)(ws + 2441216);     // 128 KB [b][8][128] partials
    float* esum_p = (float*)(ws + 2572288);     // 1 KB
    u16*   weC    = (u16*)  (ws + 4194304);     // 2 MB  [m=s*32+b][128] bf16
    float* lab_e  = (float*)(ws + 8388608);     // 1 MB
    float* sent_h = (float*)(ws + 9437184);     // 4 MB
    float* gpre4  = (float*)(ws + 16777216);    // 32 MiB (pre-scaled, K5 layout)
    float* feat   = (float*)(ws + 50331648);    // 8 MB  [b][s][256]

    // canonical sub-offsets (elements)
    float* sentBc = can + 20480;
    float* convWc = can + 20608;
    float* convBc = can + 23680;
    float* Wfc    = can + 23712;
    float* Wbc    = can + 154784;
    float* bfc    = can + 285856;
    float* bbc    = can + 286368;
    float* Ufc    = can + 286880;
    float* Ubc    = can + 352416;
    float* tagBc  = can + 426144;
    float* memBc  = can + 434368;

    static const int cn_n[15]   = {4096,16384,128,3072,32,131072,131072,512,512,65536,65536,8192,32,8192,32};
    static const int cn_src[15] = {8,9,10,11,12,13,16,15,18,14,17,19,20,21,22};
    PJobs jb;
    {
        int off = 0;
        for (int i=0;i<15;i++){
            jb.src[i]=d_in[cn_src[i]]; jb.n[i]=cn_n[i]; jb.p0[i]=off; jb.p1[i]=0; jb.type[i]=0;
            off+=cn_n[i];
        }
        jb.src[15]=d_in[13]; jb.n[15]=65536; jb.p0[15]=0;    jb.p1[15]=512; jb.type[15]=1; // Wf[:128]
        jb.src[16]=d_in[16]; jb.n[16]=65536; jb.p0[16]=512;  jb.p1[16]=512; jb.type[16]=1; // Wb[:128]
        jb.src[17]=d_in[9];  jb.n[17]=16384; jb.p0[17]=1024; jb.p1[17]=128; jb.type[17]=1; // sentW
        jb.src[18]=d_in[19]; jb.n[18]=8192;  jb.p0[18]=0;    jb.p1[18]=0;   jb.type[18]=2;
        jb.src[19]=d_in[21]; jb.n[19]=8192;  jb.p0[19]=1;    jb.p1[19]=0;   jb.type[19]=2;
        jb.src[20]=d_in[8];  jb.n[20]=4096;  jb.p0[20]=0;    jb.p1[20]=0;   jb.type[20]=3; // label norm
    }

    kprep  <<<dim3(512,21), 256, 0, stream>>>(jb, d_in[7], flags, can, WcatT, tagWT, memWT);
    k1_token<<<8192, 128, 0, stream>>>(wid, d_in[7], flags, weC, invn);
    kgemm  <<<dim3(128,19), 256, 0, stream>>>(weC, WcatT, invn, sentBc, gpre4, sent_h, lab_e);
    k2_conv<<<dim3(32,8), 256, 0, stream>>>(lab_e, convWc, convBc, lens, e_ws);
    k3a_attn<<<dim3(32,8), 256, 0, stream>>>(e_ws, sent_h, srp, esum_p);
    k3b_cpart<<<dim3(4,32), 256, 0, stream>>>(srp, esum_p, Wfc, Wbc, bfc, bbc, cpart);
    k5_lstm<<<16, 512, 0, stream>>>(gpre4, Ufc, Ubc, cpart, lens, feat);
    k6_final<<<1024, 256, 0, stream>>>(feat, wid, lens, tagWT, tagBc, memWT, memBc,
                                       d_in[23], flags, d_out);
}

// Round 9
// 223.414 us; speedup vs baseline: 1.6282x; 1.0794x over previous
//
#include <hip/hip_runtime.h>
#include <hip/hip_bf16.h>

#define BB 32
#define SS 256
#define DD 128
#define GG 128
#define NG 512   // 4*(H/2) gate columns per direction
#define LL 32
#define LOG2E 1.4426950408889634f

typedef unsigned short u16;
typedef __attribute__((ext_vector_type(8))) short short8;
typedef __attribute__((ext_vector_type(4))) float f32x4;

__device__ __forceinline__ float bf2f(u16 u){ return __uint_as_float(((unsigned)u)<<16); }
__device__ __forceinline__ u16 f2bf(float f){
    unsigned x = __float_as_uint(f);
    unsigned r = x + 0x7fffu + ((x>>16)&1u);
    return (u16)(r>>16);
}
__device__ __forceinline__ float tanh_f(float x){ float e=__expf(2.0f*x); return 1.0f - 2.0f/(e+1.0f); }

__device__ __forceinline__ float exp2_f(float x){
#if __has_builtin(__builtin_amdgcn_exp2f)
    return __builtin_amdgcn_exp2f(x);
#elif __has_builtin(__builtin_amdgcn_expf)
    return __builtin_amdgcn_expf(x);
#else
    return __expf(x * 0.6931471805599453f);
#endif
}
__device__ __forceinline__ float rcp_f(float x){
#if __has_builtin(__builtin_amdgcn_rcpf)
    return __builtin_amdgcn_rcpf(x);
#else
    return 1.0f / x;
#endif
}

// ---------------- kprep: dtype flag + canonicalize + transposes + label-norm ----------------
// type 0: can[p0+i] = f32(src[i])
// type 1: WcatT[(p0 + c)*128 + k] = bf16(src[k*p1 + c])            (plain W^T)
// type 2: (p0? memWT : tagWT)[(i&31)*256 + (i>>5)] = bf16(...)
// type 3: label row-norm -> WcatT cols 1152..1183 (+ zero pad)
// type 4: gate W^T with q-permute: col c = q*128+w5*16+li -> row p0 + w5*64+q*16+li
struct PJobs { const void* src[21]; int n[21]; int p0[21]; int p1[21]; int type[21]; };

__global__ void kprep(PJobs jb, const void* __restrict__ wemb, int* __restrict__ flags,
                      float* __restrict__ can,
                      u16* __restrict__ WcatT, u16* __restrict__ tagWT, u16* __restrict__ memWT){
    int t = threadIdx.x;
    __shared__ int cw[4];
    __shared__ int sflag;
    {
        u16 v = ((const u16*)wemb)[2*t];
        int e = (v>>7)&0xFF;
        int c = (e>=0x90)?1:0;
        #pragma unroll
        for (int mk=32; mk>0; mk>>=1) c += __shfl_xor(c, mk);
        if ((t&63)==0) cw[t>>6] = c;
        __syncthreads();
        if (t==0) sflag = (cw[0]+cw[1]+cw[2]+cw[3] >= 32) ? 1 : 0;
        __syncthreads();
    }
    int f = sflag;
    if (blockIdx.x==0 && blockIdx.y==0 && t==0) flags[0] = f;

    int id = blockIdx.y;
    int i = blockIdx.x*256 + t;
    if (i >= jb.n[id]) return;
    const void* src = jb.src[id];
    int p0 = jb.p0[id];
    int ty = jb.type[id];
    if (ty == 0){
        float v = f ? ((const float*)src)[i] : bf2f(((const u16*)src)[i]);
        can[p0 + i] = v;
    } else if (ty == 1){
        int c = i>>7, k = i&127;
        float v = f ? ((const float*)src)[k*jb.p1[id] + c] : bf2f(((const u16*)src)[k*jb.p1[id] + c]);
        WcatT[(size_t)(p0 + c)*128 + k] = f2bf(v);
    } else if (ty == 2){
        int l = i&31, k = i>>5;
        float v = f ? ((const float*)src)[k*32 + l] : bf2f(((const u16*)src)[k*32 + l]);
        (p0 ? memWT : tagWT)[l*256 + k] = f2bf(v);
    } else if (ty == 3){
        int row = i>>7, col = i&127;
        float v = f ? ((const float*)src)[i] : bf2f(((const u16*)src)[i]);
        float sq = v*v;
        #pragma unroll
        for (int mk=32; mk>0; mk>>=1) sq += __shfl_xor(sq, mk);
        __shared__ float r4[4];
        if ((t&63)==0) r4[t>>6] = sq;
        __syncthreads();
        int half = t>>7;
        float tot = r4[half*2] + r4[half*2+1];
        float inv = 1.0f/(sqrtf(tot) + 1e-8f);
        WcatT[(size_t)(1152+row)*128 + col] = f2bf(v*inv);
        WcatT[(size_t)(1184+row)*128 + col] = 0;   // pad cols
    } else {
        // type 4: gate W with q-permute (k = i&127, c = i>>7 in 0..511)
        int c = i>>7, k = i&127;
        float v = f ? ((const float*)src)[k*512 + c] : bf2f(((const u16*)src)[k*512 + c]);
        int q = c>>7, rem = c&127, w5 = rem>>4, li = rem&15;
        WcatT[(size_t)(p0 + w5*64 + q*16 + li)*128 + k] = f2bf(v);
    }
}

// ---------------- k1: gather + norm -> weC (bf16), invn ----------------
__global__ void k1_token(const int* __restrict__ wid, const void* __restrict__ wemb,
                         const int* __restrict__ flags,
                         u16* __restrict__ weC, float* __restrict__ invn){
    int blk = blockIdx.x;          // b*256+s
    int t = threadIdx.x;           // 128
    int idx = wid[blk];
    float wv = flags[0] ? ((const float*)wemb)[(size_t)idx*DD + t]
                        : bf2f(((const u16*)wemb)[(size_t)idx*DD + t]);
    int b = blk>>8, s = blk&255;
    int m = s*BB + b;
    weC[(size_t)m*DD + t] = f2bf(wv);
    float sq = wv*wv;
    #pragma unroll
    for (int mk=32; mk>0; mk>>=1) sq += __shfl_xor(sq, mk);
    __shared__ float red2[2];
    if ((t&63)==0) red2[t>>6] = sq;
    __syncthreads();
    if (t==0) invn[m] = 1.0f/(sqrtf(red2[0]+red2[1]) + 1e-8f);
}

// ---------------- kgemm: [gpre4 | sent_h | lab_e] = weC(bf16) @ WcatT(bf16), MFMA ----------------
// nb<16: (dir = nb>>3, w5 = nb&7), q-permuted cols -> f32x4-coalesced gpre4 stores.
__global__ __launch_bounds__(256) void kgemm(const u16* __restrict__ weC,
                      const u16* __restrict__ WcatT,
                      const float* __restrict__ invn, const float* __restrict__ sentBc,
                      float* __restrict__ gpre4, float* __restrict__ sent_h,
                      float* __restrict__ lab_e){
    int mt = blockIdx.x;            // 0..127
    int nb = blockIdx.y;            // 0..18
    int t = threadIdx.x;
    int w4 = t>>6, l = t&63, li = l&15, lg = l>>4;
    int mbase = mt*64 + w4*16;
    int n0 = nb*64;
    short8 af[4];
    #pragma unroll
    for (int ks=0;ks<4;ks++)
        af[ks] = *(const short8*)&weC[(size_t)(mbase + li)*128 + ks*32 + lg*8];
    f32x4 acc[4];
    #pragma unroll
    for (int nt=0;nt<4;nt++){
        short8 bf[4];
        #pragma unroll
        for (int ks=0;ks<4;ks++)
            bf[ks] = *(const short8*)&WcatT[(size_t)(n0 + nt*16 + li)*128 + ks*32 + lg*8];
        f32x4 a; a[0]=0.f; a[1]=0.f; a[2]=0.f; a[3]=0.f;
        #pragma unroll
        for (int ks=0;ks<4;ks++)
            a = __builtin_amdgcn_mfma_f32_16x16x32_bf16(af[ks], bf[ks], a, 0,0,0);
        acc[nt] = a;
    }
    if (nb < 16){
        // acc[q][r] = gate preact for (m = mbase+lg*4+r, col q*128 + w5*16 + li)
        int dir = nb>>3, w5 = nb&7;
        int s = mt*2 + (w4>>1);
        int bg = (w4&1)*4 + lg;
        float* gp = gpre4 + ((((size_t)(dir*8+bg)*256 + s)*8 + w5)*256);
        #pragma unroll
        for (int r=0;r<4;r++){
            f32x4 v;
            v[0] = acc[0][r]*LOG2E;
            v[1] = acc[1][r]*LOG2E;
            v[2] = acc[2][r]*(2.0f*LOG2E);
            v[3] = acc[3][r]*LOG2E;
            *(f32x4*)&gp[(r*16 + li)*4] = v;
        }
    } else {
        int mrow = mbase + lg*4;
        #pragma unroll
        for (int nt=0;nt<4;nt++){
            int n = n0 + nt*16 + li;
            if (n < 1152){
                int c = n - 1024;
                float bb = sentBc[c];
                #pragma unroll
                for (int r=0;r<4;r++){
                    int m = mrow + r;
                    int b = m&31, s = m>>5;
                    sent_h[((size_t)(b*256+s))*128 + c] = tanh_f(acc[nt][r] + bb);
                }
            } else if (n < 1184){
                int c = n - 1152;
                #pragma unroll
                for (int r=0;r<4;r++){
                    int m = mrow + r;
                    int b = m&31, s = m>>5;
                    lab_e[((size_t)(b*256+s))*32 + c] = acc[nt][r] * invn[m];
                }
            }
        }
    }
}

// ---------------- k23p: conv+relu+max+exp fused with partial attention sums ----------------
__global__ __launch_bounds__(256) void k23p(const float* __restrict__ lab_e,
                        const float* __restrict__ convWc, const float* __restrict__ convBc,
                        const float* __restrict__ sent_h,
                        const int* __restrict__ lens,
                        float* __restrict__ srp, float* __restrict__ esum_p){
    int b = blockIdx.x, stile = blockIdx.y, t = threadIdx.x;
    int sl = t>>3, oq = t&7;
    int s = stile*32 + sl;
    __shared__ float le_s[34*33];
    __shared__ float wle[LL*LL*3];
    __shared__ float wb[LL];
    __shared__ float es[32];
    __shared__ float red[2][GG];
    int s0 = stile*32;
    for (int i=t; i<34*32; i+=256){
        int row = i>>5, col = i&31;
        int sg = s0 - 1 + row;
        le_s[row*33 + col] = (sg>=0 && sg<SS) ? lab_e[(size_t)b*SS*LL + sg*LL + col] : 0.f;
    }
    for (int i=t; i<LL*LL*3; i+=256) wle[i] = convWc[i];
    if (t < LL) wb[t] = convBc[t];
    __syncthreads();
    float lm = 0.f;   // relu >= 0
    #pragma unroll
    for (int op=0; op<4; op++){
        int o = oq*4 + op;
        float a0 = wb[o], a1 = 0.f, a2 = 0.f;
        #pragma unroll
        for (int i=0;i<LL;i++){
            a0 = fmaf(le_s[(sl+0)*33+i], wle[o*96 + i*3    ], a0);
            a1 = fmaf(le_s[(sl+1)*33+i], wle[o*96 + i*3 + 1], a1);
            a2 = fmaf(le_s[(sl+2)*33+i], wle[o*96 + i*3 + 2], a2);
        }
        lm = fmaxf(lm, fmaxf(a0+a1+a2, 0.f));
    }
    #pragma unroll
    for (int mk=1; mk<8; mk<<=1) lm = fmaxf(lm, __shfl_xor(lm, mk));
    if (oq == 0) es[sl] = (s < lens[b]) ? __expf(lm) : 0.f;
    __syncthreads();
    // partial attention sums over this 32-s tile
    int col = t&127, sh = t>>7;
    float a0 = 0.f, a1 = 0.f;
    int sb = s0 + sh*16;
    #pragma unroll
    for (int s2=0; s2<16; s2+=2){
        a0 = fmaf(es[sh*16+s2],   sent_h[((size_t)b*SS + sb+s2)*GG + col], a0);
        a1 = fmaf(es[sh*16+s2+1], sent_h[((size_t)b*SS + sb+s2+1)*GG + col], a1);
    }
    red[sh][col] = a0+a1;
    __syncthreads();
    if (t < GG) srp[((size_t)b*8 + stile)*GG + t] = red[0][t] + red[1][t];
    if (t < 32){
        float e = es[t];
        #pragma unroll
        for (int mk=16; mk>0; mk>>=1) e += __shfl_xor(e, mk);
        if (t==0) esum_p[b*8 + stile] = e;
    }
}

// ---------------- k3b: combine partials + cpart matvec ----------------
__global__ void k3b_cpart(const float* __restrict__ srp, const float* __restrict__ esum_p,
                          const float* __restrict__ Wfc, const float* __restrict__ Wbc,
                          const float* __restrict__ bfc, const float* __restrict__ bbc,
                          float* __restrict__ cpart){
    int chunk = blockIdx.x, b = blockIdx.y, t = threadIdx.x;  // 4 x 32, 256 thr
    __shared__ float srs[GG];
    if (t < GG){
        float a = 0.f;
        #pragma unroll
        for (int st=0; st<8; st++) a += srp[((size_t)b*8 + st)*GG + t];
        float es = 0.f;
        #pragma unroll
        for (int st=0; st<8; st++) es += esum_p[b*8 + st];
        srs[t] = a * (1.0f/es);
    }
    __syncthreads();
    int ng = chunk*256 + t;          // 0..1023
    int dir = ng>>9, n = ng&511;
    const float* W = dir ? Wbc : Wfc;
    float c0 = (dir ? bbc : bfc)[n], c1 = 0.f;
    for (int g=0; g<GG; g+=2){
        c0 = fmaf(srs[g],   W[(size_t)(DD+g)*NG + n], c0);
        c1 = fmaf(srs[g+1], W[(size_t)(DD+g+1)*NG + n], c1);
    }
    cpart[((size_t)dir*NG + n)*BB + b] = c0+c1;
}

// ---------------- K5: bidir LSTM, 16 wgs, 1 cell/lane, predicated A-read ----------------
// Persistent accumulators: elements 1..3 never read (stale constants — zero A rows
// add 0 each step); only element 0 re-armed with G+cpr per step. Saves 12 movs/step.
__global__ __launch_bounds__(512) void k5_lstm(const float* __restrict__ gpre4,
                       const float* __restrict__ Ufc, const float* __restrict__ Ubc,
                       const float* __restrict__ cpart,
                       const int* __restrict__ lens, float* __restrict__ feat){
    int dir = blockIdx.x>>3, bg = blockIdx.x&7;
    int t = threadIdx.x;
    int w = t>>6, l = t&63, lg = l>>4, li = l&15;
    int j = w*16 + li;                         // hidden column 0..127
    int b = bg*4 + lg;                         // this lane's batch
    const float* Uc = dir ? Ubc : Ufc;

    short8 bfr[4][4];
    #pragma unroll
    for (int q=0;q<4;q++){
        float sc = (q==2) ? 2.0f*LOG2E : LOG2E;
        #pragma unroll
        for (int ks=0;ks<4;ks++){
            int n = q*128 + j;
            short8 v;
            #pragma unroll
            for (int jj=0;jj<8;jj++)
                v[jj] = (short)f2bf(Uc[(size_t)(ks*32 + lg*8 + jj)*NG + n] * sc);
            bfr[q][ks] = v;
        }
    }
    float cpr[4];
    #pragma unroll
    for (int q=0;q<4;q++)
        cpr[q] = cpart[((size_t)(dir*NG + q*128 + j))*BB + b] * ((q==2) ? 2.0f*LOG2E : LOG2E);
    int len1 = lens[b];

    __shared__ u16 Hhi[2][16*128];   // XOR-swizzled, double-buffered
    for (int i=t; i<2*2048; i+=512) ((u16*)Hhi)[i] = 0;

    bool rdp = ((li & 3) == 0);      // only 16 lanes/wave read the A tile
    int roff[4];
    #pragma unroll
    for (int ks=0;ks<4;ks++)
        roff[ks] = (li*256 + ((ks*64 + lg*16) ^ ((li&7)<<4))) >> 1;
    int woff;
    { int row = lg*4; woff = (row*256 + ((2*j) ^ ((row&7)<<4))) >> 1; }

    short8 ah[4];
    #pragma unroll
    for (int ks=0;ks<4;ks++){
        #pragma unroll
        for (int jj=0;jj<8;jj++) ah[ks][jj] = 0;
    }
    f32x4 acv[4];
    #pragma unroll
    for (int q=0;q<4;q++){ acv[q][0]=0.f; acv[q][1]=0.f; acv[q][2]=0.f; acv[q][3]=0.f; }

    float c = 0.f, h = 0.f;
    int sgn = dir ? -1 : 1;
    int s0 = dir ? (SS-1) : 0;
    const float* gl = gpre4 + ((size_t)(dir*8 + bg)*256 + s0)*2048 + w*256 + l*4;
    ptrdiff_t gstep = (ptrdiff_t)sgn * 2048;

    f32x4 gA = *(const f32x4*)gl;
    f32x4 gB = *(const f32x4*)(gl + gstep);
    const float* glp = gl + 2*gstep;

    float* fb = feat + ((size_t)b*SS + s0)*256 + dir*128 + j;
    ptrdiff_t fstep = (ptrdiff_t)sgn * 256;

    int s = s0;
    __syncthreads();

#define K5_STEP(P, G)                                                          \
    {                                                                          \
        if (rdp){                                                              \
            ah[0] = *(const short8*)&Hhi[P][roff[0]];                          \
            ah[1] = *(const short8*)&Hhi[P][roff[1]];                          \
            ah[2] = *(const short8*)&Hhi[P][roff[2]];                          \
            ah[3] = *(const short8*)&Hhi[P][roff[3]];                          \
        }                                                                      \
        acv[0][0] = G[0]+cpr[0];                                               \
        acv[1][0] = G[1]+cpr[1];                                               \
        acv[2][0] = G[2]+cpr[2];                                               \
        acv[3][0] = G[3]+cpr[3];                                               \
        if (tt2 + 2 < SS){ G = *(const f32x4*)glp; glp += gstep; }             \
        _Pragma("unroll")                                                      \
        for (int ks=0;ks<4;ks++){                                              \
            _Pragma("unroll")                                                  \
            for (int q=0;q<4;q++)                                              \
                acv[q] = __builtin_amdgcn_mfma_f32_16x16x32_bf16(ah[ks], bfr[q][ks], acv[q], 0,0,0); \
        }                                                                      \
        float si = rcp_f(1.0f + exp2_f(-acv[0][0]));                           \
        float sf = rcp_f(1.0f + exp2_f(-acv[1][0]));                           \
        float tg = 1.0f - 2.0f*rcp_f(exp2_f(acv[2][0]) + 1.0f);                \
        float so = rcp_f(1.0f + exp2_f(-acv[3][0]));                           \
        float cn = sf*c + si*tg;                                               \
        float th = 1.0f - 2.0f*rcp_f(exp2_f(cn*(2.0f*LOG2E)) + 1.0f);          \
        float hn = so*th;                                                      \
        if (s < 128){ c = cn; h = hn; fb[0] = hn; }                            \
        else { bool mm = (s < len1); c = mm?cn:c; h = mm?hn:h; fb[0] = mm?hn:0.f; } \
        Hhi[P^1][woff] = f2bf(h);                                              \
        asm volatile("s_waitcnt lgkmcnt(0)" ::: "memory");                     \
        __builtin_amdgcn_sched_barrier(0);                                     \
        __builtin_amdgcn_s_barrier();                                          \
        __builtin_amdgcn_sched_barrier(0);                                     \
        s += sgn; fb += fstep;                                                 \
    }

    for (int tt=0; tt<SS; tt+=2){
        { int tt2 = tt;   K5_STEP(0, gA) }
        { int tt2 = tt+1; K5_STEP(1, gB) }
    }
#undef K5_STEP
}

// ---------------- k6: tag/mem projections + blend ----------------
__global__ void k6_final(const float* __restrict__ feat, const int* __restrict__ wid,
                         const int* __restrict__ lens,
                         const u16* __restrict__ tagWT, const float* __restrict__ tagBc,
                         const u16* __restrict__ memWT, const float* __restrict__ memBc,
                         const void* __restrict__ bank, const int* __restrict__ flags,
                         void* __restrict__ out){
    int t = threadIdx.x;
    int tok = blockIdx.x*8 + (t>>5);
    int lcol = t&31;
    int b = tok>>8, s = tok&255;
    int f32m = flags[0];
    int idx = wid[tok];
    bool m = s < lens[b];
    const float* fr = feat + (size_t)tok*256;
    float a0 = tagBc[lcol], a1=0.f, a2=0.f, a3=0.f;
    #pragma unroll 4
    for (int cc=0; cc<32; cc++){
        short8 tw = *(const short8*)&tagWT[lcol*256 + cc*8];
        a0 = fmaf(fr[cc*8+0], bf2f((u16)tw[0]), a0);
        a1 = fmaf(fr[cc*8+1], bf2f((u16)tw[1]), a1);
        a2 = fmaf(fr[cc*8+2], bf2f((u16)tw[2]), a2);
        a3 = fmaf(fr[cc*8+3], bf2f((u16)tw[3]), a3);
        a0 = fmaf(fr[cc*8+4], bf2f((u16)tw[4]), a0);
        a1 = fmaf(fr[cc*8+5], bf2f((u16)tw[5]), a1);
        a2 = fmaf(fr[cc*8+6], bf2f((u16)tw[6]), a2);
        a3 = fmaf(fr[cc*8+7], bf2f((u16)tw[7]), a3);
    }
    float r1 = (a0+a1)+(a2+a3);
    float b0 = memBc[lcol], b1=0.f, b2=0.f, b3=0.f;
    if (m){
        if (f32m){
            const float* br = (const float*)bank + (size_t)idx*256;
            #pragma unroll 4
            for (int cc=0; cc<32; cc++){
                short8 tw = *(const short8*)&memWT[lcol*256 + cc*8];
                b0 = fmaf(br[cc*8+0], bf2f((u16)tw[0]), b0);
                b1 = fmaf(br[cc*8+1], bf2f((u16)tw[1]), b1);
                b2 = fmaf(br[cc*8+2], bf2f((u16)tw[2]), b2);
                b3 = fmaf(br[cc*8+3], bf2f((u16)tw[3]), b3);
                b0 = fmaf(br[cc*8+4], bf2f((u16)tw[4]), b0);
                b1 = fmaf(br[cc*8+5], bf2f((u16)tw[5]), b1);
                b2 = fmaf(br[cc*8+6], bf2f((u16)tw[6]), b2);
                b3 = fmaf(br[cc*8+7], bf2f((u16)tw[7]), b3);
            }
        } else {
            const u16* br = (const u16*)bank + (size_t)idx*256;
            #pragma unroll 4
            for (int cc=0; cc<32; cc++){
                short8 tw = *(const short8*)&memWT[lcol*256 + cc*8];
                short8 bv = *(const short8*)&br[cc*8];
                b0 = fmaf(bf2f((u16)bv[0]), bf2f((u16)tw[0]), b0);
                b1 = fmaf(bf2f((u16)bv[1]), bf2f((u16)tw[1]), b1);
                b2 = fmaf(bf2f((u16)bv[2]), bf2f((u16)tw[2]), b2);
                b3 = fmaf(bf2f((u16)bv[3]), bf2f((u16)tw[3]), b3);
                b0 = fmaf(bf2f((u16)bv[4]), bf2f((u16)tw[4]), b0);
                b1 = fmaf(bf2f((u16)bv[5]), bf2f((u16)tw[5]), b1);
                b2 = fmaf(bf2f((u16)bv[6]), bf2f((u16)tw[6]), b2);
                b3 = fmaf(bf2f((u16)bv[7]), bf2f((u16)tw[7]), b3);
            }
        }
    }
    float r2 = (b0+b1)+(b2+b3);
    float res = 0.5f*r1 + 0.5f*r2;
    if (f32m) ((float*)out)[(size_t)tok*LL + lcol] = res;
    else      ((u16*)out)[(size_t)tok*LL + lcol]   = f2bf(res);
}

extern "C" void kernel_launch(void* const* d_in, const int* in_sizes, int n_in,
                              void* d_out, int out_size, void* d_ws, size_t ws_size,
                              hipStream_t stream){
    const int* wid  = (const int*)d_in[0];
    const int* lens = (const int*)d_in[1];
    // d_in[2..6]: char_*, mask, idx_inputs — unused (mask recomputed from lens)

    char* ws = (char*)d_ws;
    int*   flags  = (int*)  (ws + 0);
    float* can    = (float*)(ws + 1024);        // 1.74 MB canonical f32 weights
    u16*   WcatT  = (u16*)  (ws + 1900544);     // 1216x128 bf16 = 304 KB
    u16*   tagWT  = (u16*)  (ws + 2211840);     // 16 KB
    u16*   memWT  = (u16*)  (ws + 2228224);     // 16 KB
    float* invn   = (float*)(ws + 2244608);     // 32 KB
    float* cpart  = (float*)(ws + 2277376);     // 128 KB [dir][n][b]
    float* srp    = (float*)(ws + 2441216);     // 128 KB [b][8][128] partials
    float* esum_p = (float*)(ws + 2572288);     // 1 KB
    u16*   weC    = (u16*)  (ws + 4194304);     // 2 MB  [m=s*32+b][128] bf16
    float* lab_e  = (float*)(ws + 8388608);     // 1 MB
    float* sent_h = (float*)(ws + 9437184);     // 4 MB
    float* gpre4  = (float*)(ws + 16777216);    // 32 MiB (pre-scaled, K5 layout)
    float* feat   = (float*)(ws + 50331648);    // 8 MB  [b][s][256]

    // canonical sub-offsets (elements)
    float* sentBc = can + 20480;
    float* convWc = can + 20608;
    float* convBc = can + 23680;
    float* Wfc    = can + 23712;
    float* Wbc    = can + 154784;
    float* bfc    = can + 285856;
    float* bbc    = can + 286368;
    float* Ufc    = can + 286880;
    float* Ubc    = can + 352416;
    float* tagBc  = can + 426144;
    float* memBc  = can + 434368;

    static const int cn_n[15]   = {4096,16384,128,3072,32,131072,131072,512,512,65536,65536,8192,32,8192,32};
    static const int cn_src[15] = {8,9,10,11,12,13,16,15,18,14,17,19,20,21,22};
    PJobs jb;
    {
        int off = 0;
        for (int i=0;i<15;i++){
            jb.src[i]=d_in[cn_src[i]]; jb.n[i]=cn_n[i]; jb.p0[i]=off; jb.p1[i]=0; jb.type[i]=0;
            off+=cn_n[i];
        }
        jb.src[15]=d_in[13]; jb.n[15]=65536; jb.p0[15]=0;    jb.p1[15]=512; jb.type[15]=4; // Wf[:128] q-perm
        jb.src[16]=d_in[16]; jb.n[16]=65536; jb.p0[16]=512;  jb.p1[16]=512; jb.type[16]=4; // Wb[:128] q-perm
        jb.src[17]=d_in[9];  jb.n[17]=16384; jb.p0[17]=1024; jb.p1[17]=128; jb.type[17]=1; // sentW
        jb.src[18]=d_in[19]; jb.n[18]=8192;  jb.p0[18]=0;    jb.p1[18]=0;   jb.type[18]=2;
        jb.src[19]=d_in[21]; jb.n[19]=8192;  jb.p0[19]=1;    jb.p1[19]=0;   jb.type[19]=2;
        jb.src[20]=d_in[8];  jb.n[20]=4096;  jb.p0[20]=0;    jb.p1[20]=0;   jb.type[20]=3; // label norm
    }

    kprep  <<<dim3(512,21), 256, 0, stream>>>(jb, d_in[7], flags, can, WcatT, tagWT, memWT);
    k1_token<<<8192, 128, 0, stream>>>(wid, d_in[7], flags, weC, invn);
    kgemm  <<<dim3(128,19), 256, 0, stream>>>(weC, WcatT, invn, sentBc, gpre4, sent_h, lab_e);
    k23p   <<<dim3(32,8), 256, 0, stream>>>(lab_e, convWc, convBc, sent_h, lens, srp, esum_p);
    k3b_cpart<<<dim3(4,32), 256, 0, stream>>>(srp, esum_p, Wfc, Wbc, bfc, bbc, cpart);
    k5_lstm<<<16, 512, 0, stream>>>(gpre4, Ufc, Ubc, cpart, lens, feat);
    k6_final<<<1024, 256, 0, stream>>>(feat, wid, lens, tagWT, tagBc, memWT, memBc,
                                       d_in[23], flags, d_out);
}

// Round 10
// 209.802 us; speedup vs baseline: 1.7338x; 1.0649x over previous
//
#include <hip/hip_runtime.h>
#include <hip/hip_bf16.h>

#define BB 32
#define SS 256
#define DD 128
#define GG 128
#define NG 512   // 4*(H/2) gate columns per direction
#define LL 32
#define LOG2E 1.4426950408889634f

typedef unsigned short u16;
typedef __attribute__((ext_vector_type(8))) short short8;
typedef __attribute__((ext_vector_type(4))) float f32x4;

__device__ __forceinline__ float bf2f(u16 u){ return __uint_as_float(((unsigned)u)<<16); }
__device__ __forceinline__ u16 f2bf(float f){
    unsigned x = __float_as_uint(f);
    unsigned r = x + 0x7fffu + ((x>>16)&1u);
    return (u16)(r>>16);
}
__device__ __forceinline__ float tanh_f(float x){ float e=__expf(2.0f*x); return 1.0f - 2.0f/(e+1.0f); }

__device__ __forceinline__ float exp2_f(float x){
#if __has_builtin(__builtin_amdgcn_exp2f)
    return __builtin_amdgcn_exp2f(x);
#elif __has_builtin(__builtin_amdgcn_expf)
    return __builtin_amdgcn_expf(x);
#else
    return __expf(x * 0.6931471805599453f);
#endif
}
__device__ __forceinline__ float rcp_f(float x){
#if __has_builtin(__builtin_amdgcn_rcpf)
    return __builtin_amdgcn_rcpf(x);
#else
    return 1.0f / x;
#endif
}

// ---------------- kprep: dtype flag + canonicalize + transposes + label-norm ----------------
// type 0: can[p0+i] = f32(src[i])
// type 1: WcatT[(p0 + c)*128 + k] = bf16(src[k*p1 + c])            (plain W^T)
// type 2: (p0? memWT : tagWT)[(i&31)*256 + (i>>5)] = bf16(...)
// type 3: label row-norm -> WcatT cols 1152..1183 (+ zero pad)
// type 4: gate W^T with q-permute: col c = q*128+w5*16+li -> row p0 + w5*64+q*16+li
struct PJobs { const void* src[21]; int n[21]; int p0[21]; int p1[21]; int type[21]; };

__global__ void kprep(PJobs jb, const void* __restrict__ wemb, int* __restrict__ flags,
                      float* __restrict__ can,
                      u16* __restrict__ WcatT, u16* __restrict__ tagWT, u16* __restrict__ memWT){
    int t = threadIdx.x;
    __shared__ int cw[4];
    __shared__ int sflag;
    {
        u16 v = ((const u16*)wemb)[2*t];
        int e = (v>>7)&0xFF;
        int c = (e>=0x90)?1:0;
        #pragma unroll
        for (int mk=32; mk>0; mk>>=1) c += __shfl_xor(c, mk);
        if ((t&63)==0) cw[t>>6] = c;
        __syncthreads();
        if (t==0) sflag = (cw[0]+cw[1]+cw[2]+cw[3] >= 32) ? 1 : 0;
        __syncthreads();
    }
    int f = sflag;
    if (blockIdx.x==0 && blockIdx.y==0 && t==0) flags[0] = f;

    int id = blockIdx.y;
    int i = blockIdx.x*256 + t;
    if (i >= jb.n[id]) return;
    const void* src = jb.src[id];
    int p0 = jb.p0[id];
    int ty = jb.type[id];
    if (ty == 0){
        float v = f ? ((const float*)src)[i] : bf2f(((const u16*)src)[i]);
        can[p0 + i] = v;
    } else if (ty == 1){
        int c = i>>7, k = i&127;
        float v = f ? ((const float*)src)[k*jb.p1[id] + c] : bf2f(((const u16*)src)[k*jb.p1[id] + c]);
        WcatT[(size_t)(p0 + c)*128 + k] = f2bf(v);
    } else if (ty == 2){
        int l = i&31, k = i>>5;
        float v = f ? ((const float*)src)[k*32 + l] : bf2f(((const u16*)src)[k*32 + l]);
        (p0 ? memWT : tagWT)[l*256 + k] = f2bf(v);
    } else if (ty == 3){
        int row = i>>7, col = i&127;
        float v = f ? ((const float*)src)[i] : bf2f(((const u16*)src)[i]);
        float sq = v*v;
        #pragma unroll
        for (int mk=32; mk>0; mk>>=1) sq += __shfl_xor(sq, mk);
        __shared__ float r4[4];
        if ((t&63)==0) r4[t>>6] = sq;
        __syncthreads();
        int half = t>>7;
        float tot = r4[half*2] + r4[half*2+1];
        float inv = 1.0f/(sqrtf(tot) + 1e-8f);
        WcatT[(size_t)(1152+row)*128 + col] = f2bf(v*inv);
        WcatT[(size_t)(1184+row)*128 + col] = 0;   // pad cols
    } else {
        // type 4: gate W with q-permute (k = i&127, c = i>>7 in 0..511)
        int c = i>>7, k = i&127;
        float v = f ? ((const float*)src)[k*512 + c] : bf2f(((const u16*)src)[k*512 + c]);
        int q = c>>7, rem = c&127, w5 = rem>>4, li = rem&15;
        WcatT[(size_t)(p0 + w5*64 + q*16 + li)*128 + k] = f2bf(v);
    }
}

// ---------------- k1: gather + norm -> weC (bf16), invn  (8 tokens/block, vectorized) ----------------
__global__ __launch_bounds__(256) void k1_token(const int* __restrict__ wid,
                         const void* __restrict__ wemb,
                         const int* __restrict__ flags,
                         u16* __restrict__ weC, float* __restrict__ invn){
    int t = threadIdx.x;
    int tl = t>>5, lane = t&31;
    int tok = blockIdx.x*8 + tl;        // 1024 blocks
    int idx = wid[tok];
    float v0,v1,v2,v3;
    if (flags[0]){
        f32x4 u = *(const f32x4*)((const float*)wemb + (size_t)idx*DD + lane*4);
        v0=u[0]; v1=u[1]; v2=u[2]; v3=u[3];
    } else {
        ushort4 u = *(const ushort4*)((const u16*)wemb + (size_t)idx*DD + lane*4);
        v0=bf2f(u.x); v1=bf2f(u.y); v2=bf2f(u.z); v3=bf2f(u.w);
    }
    int b = tok>>8, s = tok&255;
    int m = s*BB + b;
    ushort4 wv;
    wv.x=f2bf(v0); wv.y=f2bf(v1); wv.z=f2bf(v2); wv.w=f2bf(v3);
    *(ushort4*)&weC[(size_t)m*DD + lane*4] = wv;
    float sq = v0*v0 + v1*v1 + v2*v2 + v3*v3;
    #pragma unroll
    for (int mk=16; mk>0; mk>>=1) sq += __shfl_xor(sq, mk);
    if (lane==0) invn[m] = 1.0f/(sqrtf(sq) + 1e-8f);
}

// ---------------- kgemm: [gpre4 | sent_h | lab_e] = weC(bf16) @ WcatT(bf16), MFMA ----------------
// nb<16: (dir = nb>>3, w5 = nb&7), q-permuted cols -> f32x4-coalesced gpre4 stores.
__global__ __launch_bounds__(256) void kgemm(const u16* __restrict__ weC,
                      const u16* __restrict__ WcatT,
                      const float* __restrict__ invn, const float* __restrict__ sentBc,
                      float* __restrict__ gpre4, float* __restrict__ sent_h,
                      float* __restrict__ lab_e){
    int mt = blockIdx.x;            // 0..127
    int nb = blockIdx.y;            // 0..18
    int t = threadIdx.x;
    int w4 = t>>6, l = t&63, li = l&15, lg = l>>4;
    int mbase = mt*64 + w4*16;
    int n0 = nb*64;
    short8 af[4];
    #pragma unroll
    for (int ks=0;ks<4;ks++)
        af[ks] = *(const short8*)&weC[(size_t)(mbase + li)*128 + ks*32 + lg*8];
    f32x4 acc[4];
    #pragma unroll
    for (int nt=0;nt<4;nt++){
        short8 bf[4];
        #pragma unroll
        for (int ks=0;ks<4;ks++)
            bf[ks] = *(const short8*)&WcatT[(size_t)(n0 + nt*16 + li)*128 + ks*32 + lg*8];
        f32x4 a; a[0]=0.f; a[1]=0.f; a[2]=0.f; a[3]=0.f;
        #pragma unroll
        for (int ks=0;ks<4;ks++)
            a = __builtin_amdgcn_mfma_f32_16x16x32_bf16(af[ks], bf[ks], a, 0,0,0);
        acc[nt] = a;
    }
    if (nb < 16){
        // acc[q][r] = gate preact for (m = mbase+lg*4+r, col q*128 + w5*16 + li)
        int dir = nb>>3, w5 = nb&7;
        int s = mt*2 + (w4>>1);
        int bg = (w4&1)*4 + lg;
        float* gp = gpre4 + ((((size_t)(dir*8+bg)*256 + s)*8 + w5)*256);
        #pragma unroll
        for (int r=0;r<4;r++){
            f32x4 v;
            v[0] = acc[0][r]*LOG2E;
            v[1] = acc[1][r]*LOG2E;
            v[2] = acc[2][r]*(2.0f*LOG2E);
            v[3] = acc[3][r]*LOG2E;
            *(f32x4*)&gp[(r*16 + li)*4] = v;
        }
    } else {
        int mrow = mbase + lg*4;
        #pragma unroll
        for (int nt=0;nt<4;nt++){
            int n = n0 + nt*16 + li;
            if (n < 1152){
                int c = n - 1024;
                float bb = sentBc[c];
                #pragma unroll
                for (int r=0;r<4;r++){
                    int m = mrow + r;
                    int b = m&31, s = m>>5;
                    sent_h[((size_t)(b*256+s))*128 + c] = tanh_f(acc[nt][r] + bb);
                }
            } else if (n < 1184){
                int c = n - 1152;
                #pragma unroll
                for (int r=0;r<4;r++){
                    int m = mrow + r;
                    int b = m&31, s = m>>5;
                    lab_e[((size_t)(b*256+s))*32 + c] = acc[nt][r] * invn[m];
                }
            }
        }
    }
}

// ---------------- k23p: conv+relu+max+exp fused with partial attention sums ----------------
__global__ __launch_bounds__(256) void k23p(const float* __restrict__ lab_e,
                        const float* __restrict__ convWc, const float* __restrict__ convBc,
                        const float* __restrict__ sent_h,
                        const int* __restrict__ lens,
                        float* __restrict__ srp, float* __restrict__ esum_p){
    int b = blockIdx.x, stile = blockIdx.y, t = threadIdx.x;
    int sl = t>>3, oq = t&7;
    int s = stile*32 + sl;
    __shared__ float le_s[34*33];
    __shared__ float wle[LL*LL*3];
    __shared__ float wb[LL];
    __shared__ float es[32];
    __shared__ float red[2][GG];
    int s0 = stile*32;
    for (int i=t; i<34*32; i+=256){
        int row = i>>5, col = i&31;
        int sg = s0 - 1 + row;
        le_s[row*33 + col] = (sg>=0 && sg<SS) ? lab_e[(size_t)b*SS*LL + sg*LL + col] : 0.f;
    }
    for (int i=t; i<LL*LL*3; i+=256) wle[i] = convWc[i];
    if (t < LL) wb[t] = convBc[t];
    __syncthreads();
    float lm = 0.f;   // relu >= 0
    #pragma unroll
    for (int op=0; op<4; op++){
        int o = oq*4 + op;
        float a0 = wb[o], a1 = 0.f, a2 = 0.f;
        #pragma unroll
        for (int i=0;i<LL;i++){
            a0 = fmaf(le_s[(sl+0)*33+i], wle[o*96 + i*3    ], a0);
            a1 = fmaf(le_s[(sl+1)*33+i], wle[o*96 + i*3 + 1], a1);
            a2 = fmaf(le_s[(sl+2)*33+i], wle[o*96 + i*3 + 2], a2);
        }
        lm = fmaxf(lm, fmaxf(a0+a1+a2, 0.f));
    }
    #pragma unroll
    for (int mk=1; mk<8; mk<<=1) lm = fmaxf(lm, __shfl_xor(lm, mk));
    if (oq == 0) es[sl] = (s < lens[b]) ? __expf(lm) : 0.f;
    __syncthreads();
    // partial attention sums over this 32-s tile
    int col = t&127, sh = t>>7;
    float a0 = 0.f, a1 = 0.f;
    int sb = s0 + sh*16;
    #pragma unroll
    for (int s2=0; s2<16; s2+=2){
        a0 = fmaf(es[sh*16+s2],   sent_h[((size_t)b*SS + sb+s2)*GG + col], a0);
        a1 = fmaf(es[sh*16+s2+1], sent_h[((size_t)b*SS + sb+s2+1)*GG + col], a1);
    }
    red[sh][col] = a0+a1;
    __syncthreads();
    if (t < GG) srp[((size_t)b*8 + stile)*GG + t] = red[0][t] + red[1][t];
    if (t < 32){
        float e = es[t];
        #pragma unroll
        for (int mk=16; mk>0; mk>>=1) e += __shfl_xor(e, mk);
        if (t==0) esum_p[b*8 + stile] = e;
    }
}

// ---------------- k3b: combine partials + cpart matvec ----------------
__global__ void k3b_cpart(const float* __restrict__ srp, const float* __restrict__ esum_p,
                          const float* __restrict__ Wfc, const float* __restrict__ Wbc,
                          const float* __restrict__ bfc, const float* __restrict__ bbc,
                          float* __restrict__ cpart){
    int chunk = blockIdx.x, b = blockIdx.y, t = threadIdx.x;  // 4 x 32, 256 thr
    __shared__ float srs[GG];
    if (t < GG){
        float a = 0.f;
        #pragma unroll
        for (int st=0; st<8; st++) a += srp[((size_t)b*8 + st)*GG + t];
        float es = 0.f;
        #pragma unroll
        for (int st=0; st<8; st++) es += esum_p[b*8 + st];
        srs[t] = a * (1.0f/es);
    }
    __syncthreads();
    int ng = chunk*256 + t;          // 0..1023
    int dir = ng>>9, n = ng&511;
    const float* W = dir ? Wbc : Wfc;
    float c0 = (dir ? bbc : bfc)[n], c1 = 0.f;
    for (int g=0; g<GG; g+=2){
        c0 = fmaf(srs[g],   W[(size_t)(DD+g)*NG + n], c0);
        c1 = fmaf(srs[g+1], W[(size_t)(DD+g+1)*NG + n], c1);
    }
    cpart[((size_t)dir*NG + n)*BB + b] = c0+c1;
}

// ---------------- K5: bidir LSTM, 16 wgs, 1 cell/lane, predicated A-read ----------------
// Persistent accumulators: elements 1..3 never read (stale constants — zero A rows
// add 0 each step); only element 0 re-armed with G+cpr per step.
__global__ __launch_bounds__(512) void k5_lstm(const float* __restrict__ gpre4,
                       const float* __restrict__ Ufc, const float* __restrict__ Ubc,
                       const float* __restrict__ cpart,
                       const int* __restrict__ lens, float* __restrict__ feat){
    int dir = blockIdx.x>>3, bg = blockIdx.x&7;
    int t = threadIdx.x;
    int w = t>>6, l = t&63, lg = l>>4, li = l&15;
    int j = w*16 + li;                         // hidden column 0..127
    int b = bg*4 + lg;                         // this lane's batch
    const float* Uc = dir ? Ubc : Ufc;

    short8 bfr[4][4];
    #pragma unroll
    for (int q=0;q<4;q++){
        float sc = (q==2) ? 2.0f*LOG2E : LOG2E;
        #pragma unroll
        for (int ks=0;ks<4;ks++){
            int n = q*128 + j;
            short8 v;
            #pragma unroll
            for (int jj=0;jj<8;jj++)
                v[jj] = (short)f2bf(Uc[(size_t)(ks*32 + lg*8 + jj)*NG + n] * sc);
            bfr[q][ks] = v;
        }
    }
    float cpr[4];
    #pragma unroll
    for (int q=0;q<4;q++)
        cpr[q] = cpart[((size_t)(dir*NG + q*128 + j))*BB + b] * ((q==2) ? 2.0f*LOG2E : LOG2E);
    int len1 = lens[b];

    __shared__ u16 Hhi[2][16*128];   // XOR-swizzled, double-buffered
    for (int i=t; i<2*2048; i+=512) ((u16*)Hhi)[i] = 0;

    bool rdp = ((li & 3) == 0);      // only 16 lanes/wave read the A tile
    int roff[4];
    #pragma unroll
    for (int ks=0;ks<4;ks++)
        roff[ks] = (li*256 + ((ks*64 + lg*16) ^ ((li&7)<<4))) >> 1;
    int woff;
    { int row = lg*4; woff = (row*256 + ((2*j) ^ ((row&7)<<4))) >> 1; }

    short8 ah[4];
    #pragma unroll
    for (int ks=0;ks<4;ks++){
        #pragma unroll
        for (int jj=0;jj<8;jj++) ah[ks][jj] = 0;
    }
    f32x4 acv[4];
    #pragma unroll
    for (int q=0;q<4;q++){ acv[q][0]=0.f; acv[q][1]=0.f; acv[q][2]=0.f; acv[q][3]=0.f; }

    float c = 0.f, h = 0.f;
    int sgn = dir ? -1 : 1;
    int s0 = dir ? (SS-1) : 0;
    const float* gl = gpre4 + ((size_t)(dir*8 + bg)*256 + s0)*2048 + w*256 + l*4;
    ptrdiff_t gstep = (ptrdiff_t)sgn * 2048;

    f32x4 gA = *(const f32x4*)gl;
    f32x4 gB = *(const f32x4*)(gl + gstep);
    const float* glp = gl + 2*gstep;

    float* fb = feat + ((size_t)b*SS + s0)*256 + dir*128 + j;
    ptrdiff_t fstep = (ptrdiff_t)sgn * 256;

    int s = s0;
    __syncthreads();

#define K5_STEP(P, G)                                                          \
    {                                                                          \
        if (rdp){                                                              \
            ah[0] = *(const short8*)&Hhi[P][roff[0]];                          \
            ah[1] = *(const short8*)&Hhi[P][roff[1]];                          \
            ah[2] = *(const short8*)&Hhi[P][roff[2]];                          \
            ah[3] = *(const short8*)&Hhi[P][roff[3]];                          \
        }                                                                      \
        acv[0][0] = G[0]+cpr[0];                                               \
        acv[1][0] = G[1]+cpr[1];                                               \
        acv[2][0] = G[2]+cpr[2];                                               \
        acv[3][0] = G[3]+cpr[3];                                               \
        if (tt2 + 2 < SS){ G = *(const f32x4*)glp; glp += gstep; }             \
        _Pragma("unroll")                                                      \
        for (int ks=0;ks<4;ks++){                                              \
            _Pragma("unroll")                                                  \
            for (int q=0;q<4;q++)                                              \
                acv[q] = __builtin_amdgcn_mfma_f32_16x16x32_bf16(ah[ks], bfr[q][ks], acv[q], 0,0,0); \
        }                                                                      \
        float si = rcp_f(1.0f + exp2_f(-acv[0][0]));                           \
        float sf = rcp_f(1.0f + exp2_f(-acv[1][0]));                           \
        float tg = 1.0f - 2.0f*rcp_f(exp2_f(acv[2][0]) + 1.0f);                \
        float so = rcp_f(1.0f + exp2_f(-acv[3][0]));                           \
        float cn = sf*c + si*tg;                                               \
        float th = 1.0f - 2.0f*rcp_f(exp2_f(cn*(2.0f*LOG2E)) + 1.0f);          \
        float hn = so*th;                                                      \
        if (s < 128){ c = cn; h = hn; fb[0] = hn; }                            \
        else { bool mm = (s < len1); c = mm?cn:c; h = mm?hn:h; fb[0] = mm?hn:0.f; } \
        Hhi[P^1][woff] = f2bf(h);                                              \
        asm volatile("s_waitcnt lgkmcnt(0)" ::: "memory");                     \
        __builtin_amdgcn_sched_barrier(0);                                     \
        __builtin_amdgcn_s_barrier();                                          \
        __builtin_amdgcn_sched_barrier(0);                                     \
        s += sgn; fb += fstep;                                                 \
    }

    for (int tt=0; tt<SS; tt+=2){
        { int tt2 = tt;   K5_STEP(0, gA) }
        { int tt2 = tt+1; K5_STEP(1, gB) }
    }
#undef K5_STEP
}

// ---------------- k6: tag/mem projections + blend (LDS-staged, vectorized) ----------------
__global__ __launch_bounds__(256) void k6_final(const float* __restrict__ feat,
                         const int* __restrict__ wid,
                         const int* __restrict__ lens,
                         const u16* __restrict__ tagWT, const float* __restrict__ tagBc,
                         const u16* __restrict__ memWT, const float* __restrict__ memBc,
                         const void* __restrict__ bank, const int* __restrict__ flags,
                         void* __restrict__ out){
    int t = threadIdx.x;
    int tl = t>>5, lcol = t&31;
    int tok0 = blockIdx.x*8;
    __shared__ float fr_s[8][256];
    __shared__ float br_s[8][256];
    __shared__ int idxs[8];
    __shared__ int msks[8];
    if (t < 8){
        int tok = tok0 + t;
        idxs[t] = wid[tok];
        msks[t] = ((tok&255) < lens[tok>>8]) ? 1 : 0;
    }
    __syncthreads();
    int f32m = flags[0];
    // stage feat rows (each thread: 8 floats = 2 x f32x4, coalesced per row)
    {
        const float* fp = feat + (size_t)(tok0+tl)*256 + lcol*8;
        f32x4 u0 = *(const f32x4*)fp;
        f32x4 u1 = *(const f32x4*)(fp+4);
        *(f32x4*)&fr_s[tl][lcol*8]   = u0;
        *(f32x4*)&fr_s[tl][lcol*8+4] = u1;
    }
    // stage bank rows (masked rows -> 0; dot then adds 0, bias-only — exact)
    if (msks[tl]){
        if (f32m){
            const float* bp = (const float*)bank + (size_t)idxs[tl]*256 + lcol*8;
            f32x4 u0 = *(const f32x4*)bp;
            f32x4 u1 = *(const f32x4*)(bp+4);
            *(f32x4*)&br_s[tl][lcol*8]   = u0;
            *(f32x4*)&br_s[tl][lcol*8+4] = u1;
        } else {
            short8 bv = *(const short8*)((const u16*)bank + (size_t)idxs[tl]*256 + lcol*8);
            #pragma unroll
            for (int e=0;e<8;e++) br_s[tl][lcol*8+e] = bf2f((u16)bv[e]);
        }
    } else {
        #pragma unroll
        for (int e=0;e<8;e++) br_s[tl][lcol*8+e] = 0.f;
    }
    __syncthreads();
    float a0 = tagBc[lcol], a1=0.f, a2=0.f, a3=0.f;
    float b0 = memBc[lcol], b1=0.f, b2=0.f, b3=0.f;
    #pragma unroll 4
    for (int cc=0; cc<32; cc++){
        short8 tw = *(const short8*)&tagWT[lcol*256 + cc*8];
        short8 mw = *(const short8*)&memWT[lcol*256 + cc*8];
        f32x4 f0 = *(const f32x4*)&fr_s[tl][cc*8];
        f32x4 f1 = *(const f32x4*)&fr_s[tl][cc*8+4];
        f32x4 g0 = *(const f32x4*)&br_s[tl][cc*8];
        f32x4 g1 = *(const f32x4*)&br_s[tl][cc*8+4];
        a0 = fmaf(f0[0], bf2f((u16)tw[0]), a0);
        a1 = fmaf(f0[1], bf2f((u16)tw[1]), a1);
        a2 = fmaf(f0[2], bf2f((u16)tw[2]), a2);
        a3 = fmaf(f0[3], bf2f((u16)tw[3]), a3);
        a0 = fmaf(f1[0], bf2f((u16)tw[4]), a0);
        a1 = fmaf(f1[1], bf2f((u16)tw[5]), a1);
        a2 = fmaf(f1[2], bf2f((u16)tw[6]), a2);
        a3 = fmaf(f1[3], bf2f((u16)tw[7]), a3);
        b0 = fmaf(g0[0], bf2f((u16)mw[0]), b0);
        b1 = fmaf(g0[1], bf2f((u16)mw[1]), b1);
        b2 = fmaf(g0[2], bf2f((u16)mw[2]), b2);
        b3 = fmaf(g0[3], bf2f((u16)mw[3]), b3);
        b0 = fmaf(g1[0], bf2f((u16)mw[4]), b0);
        b1 = fmaf(g1[1], bf2f((u16)mw[5]), b1);
        b2 = fmaf(g1[2], bf2f((u16)mw[6]), b2);
        b3 = fmaf(g1[3], bf2f((u16)mw[7]), b3);
    }
    float r1 = (a0+a1)+(a2+a3);
    float r2 = (b0+b1)+(b2+b3);
    float res = 0.5f*r1 + 0.5f*r2;
    int tok = tok0 + tl;
    if (f32m) ((float*)out)[(size_t)tok*LL + lcol] = res;
    else      ((u16*)out)[(size_t)tok*LL + lcol]   = f2bf(res);
}

extern "C" void kernel_launch(void* const* d_in, const int* in_sizes, int n_in,
                              void* d_out, int out_size, void* d_ws, size_t ws_size,
                              hipStream_t stream){
    const int* wid  = (const int*)d_in[0];
    const int* lens = (const int*)d_in[1];
    // d_in[2..6]: char_*, mask, idx_inputs — unused (mask recomputed from lens)

    char* ws = (char*)d_ws;
    int*   flags  = (int*)  (ws + 0);
    float* can    = (float*)(ws + 1024);        // 1.74 MB canonical f32 weights
    u16*   WcatT  = (u16*)  (ws + 1900544);     // 1216x128 bf16 = 304 KB
    u16*   tagWT  = (u16*)  (ws + 2211840);     // 16 KB
    u16*   memWT  = (u16*)  (ws + 2228224);     // 16 KB
    float* invn   = (float*)(ws + 2244608);     // 32 KB
    float* cpart  = (float*)(ws + 2277376);     // 128 KB [dir][n][b]
    float* srp    = (float*)(ws + 2441216);     // 128 KB [b][8][128] partials
    float* esum_p = (float*)(ws + 2572288);     // 1 KB
    u16*   weC    = (u16*)  (ws + 4194304);     // 2 MB  [m=s*32+b][128] bf16
    float* lab_e  = (float*)(ws + 8388608);     // 1 MB
    float* sent_h = (float*)(ws + 9437184);     // 4 MB
    float* gpre4  = (float*)(ws + 16777216);    // 32 MiB (pre-scaled, K5 layout)
    float* feat   = (float*)(ws + 50331648);    // 8 MB  [b][s][256]

    // canonical sub-offsets (elements)
    float* sentBc = can + 20480;
    float* convWc = can + 20608;
    float* convBc = can + 23680;
    float* Wfc    = can + 23712;
    float* Wbc    = can + 154784;
    float* bfc    = can + 285856;
    float* bbc    = can + 286368;
    float* Ufc    = can + 286880;
    float* Ubc    = can + 352416;
    float* tagBc  = can + 426144;
    float* memBc  = can + 434368;

    static const int cn_n[15]   = {4096,16384,128,3072,32,131072,131072,512,512,65536,65536,8192,32,8192,32};
    static const int cn_src[15] = {8,9,10,11,12,13,16,15,18,14,17,19,20,21,22};
    PJobs jb;
    {
        int off = 0;
        for (int i=0;i<15;i++){
            jb.src[i]=d_in[cn_src[i]]; jb.n[i]=cn_n[i]; jb.p0[i]=off; jb.p1[i]=0; jb.type[i]=0;
            off+=cn_n[i];
        }
        jb.src[15]=d_in[13]; jb.n[15]=65536; jb.p0[15]=0;    jb.p1[15]=512; jb.type[15]=4; // Wf[:128] q-perm
        jb.src[16]=d_in[16]; jb.n[16]=65536; jb.p0[16]=512;  jb.p1[16]=512; jb.type[16]=4; // Wb[:128] q-perm
        jb.src[17]=d_in[9];  jb.n[17]=16384; jb.p0[17]=1024; jb.p1[17]=128; jb.type[17]=1; // sentW
        jb.src[18]=d_in[19]; jb.n[18]=8192;  jb.p0[18]=0;    jb.p1[18]=0;   jb.type[18]=2;
        jb.src[19]=d_in[21]; jb.n[19]=8192;  jb.p0[19]=1;    jb.p1[19]=0;   jb.type[19]=2;
        jb.src[20]=d_in[8];  jb.n[20]=4096;  jb.p0[20]=0;    jb.p1[20]=0;   jb.type[20]=3; // label norm
    }

    kprep  <<<dim3(512,21), 256, 0, stream>>>(jb, d_in[7], flags, can, WcatT, tagWT, memWT);
    k1_token<<<1024, 256, 0, stream>>>(wid, d_in[7], flags, weC, invn);
    kgemm  <<<dim3(128,19), 256, 0, stream>>>(weC, WcatT, invn, sentBc, gpre4, sent_h, lab_e);
    k23p   <<<dim3(32,8), 256, 0, stream>>>(lab_e, convWc, convBc, sent_h, lens, srp, esum_p);
    k3b_cpart<<<dim3(4,32), 256, 0, stream>>>(srp, esum_p, Wfc, Wbc, bfc, bbc, cpart);
    k5_lstm<<<16, 512, 0, stream>>>(gpre4, Ufc, Ubc, cpart, lens, feat);
    k6_final<<<1024, 256, 0, stream>>>(feat, wid, lens, tagWT, tagBc, memWT, memBc,
                                       d_in[23], flags, d_out);
}